// Round 1
// baseline (3776.614 us; speedup 1.0000x reference)
//
#include <hip/hip_runtime.h>
#include <hip/hip_bf16.h>
#include <math.h>

// Problem constants
#define NTOK 1024
#define DMODEL 512
#define NHEAD 16
#define DHEAD 32
#define DFF 2048
#define NBINS 68
#define KIT 20
#define NEGV (-1e9f)

// ---------------- LayerNorm: one block per row (D=512, 256 thr, 2 elem/thr) ----------------
__global__ void ln_kernel(const float* __restrict__ x, const float* __restrict__ gm,
                          const float* __restrict__ bt, float* __restrict__ out) {
    int n = blockIdx.x;
    int tid = threadIdx.x;
    __shared__ float red[256];
    const float* row = x + (size_t)n * DMODEL;
    float a = row[tid], b = row[tid + 256];
    red[tid] = a + b;
    __syncthreads();
    for (int off = 128; off; off >>= 1) { if (tid < off) red[tid] += red[tid + off]; __syncthreads(); }
    float mu = red[0] * (1.0f / DMODEL);
    __syncthreads();
    float d0 = a - mu, d1 = b - mu;
    red[tid] = d0 * d0 + d1 * d1;
    __syncthreads();
    for (int off = 128; off; off >>= 1) { if (tid < off) red[tid] += red[tid + off]; __syncthreads(); }
    float rstd = rsqrtf(red[0] * (1.0f / DMODEL) + 1e-5f);
    out[(size_t)n * DMODEL + tid]       = d0 * rstd * gm[tid] + bt[tid];
    out[(size_t)n * DMODEL + tid + 256] = d1 * rstd * gm[tid + 256] + bt[tid + 256];
}

// ---------------- Generic f32 GEMM: C[M,N] = A[M,K] @ B[K,N]; M,N,K multiples of 32 --------
__global__ void gemm_kernel(const float* __restrict__ A, const float* __restrict__ B,
                            float* __restrict__ C, int M, int K, int N) {
    __shared__ float As[32][33];
    __shared__ float Bs[32][33];
    int tx = threadIdx.x, ty = threadIdx.y;
    int tid = ty * 16 + tx;
    int row0 = blockIdx.y * 32;
    int col0 = blockIdx.x * 32;
    float acc00 = 0.f, acc01 = 0.f, acc10 = 0.f, acc11 = 0.f;
    for (int k0 = 0; k0 < K; k0 += 32) {
        #pragma unroll
        for (int i = 0; i < 4; i++) {
            int idx = tid + i * 256;
            int r = idx >> 5, c = idx & 31;
            As[r][c] = A[(size_t)(row0 + r) * K + k0 + c];
            Bs[r][c] = B[(size_t)(k0 + r) * N + col0 + c];
        }
        __syncthreads();
        #pragma unroll
        for (int kk = 0; kk < 32; kk++) {
            float a0 = As[ty * 2][kk], a1 = As[ty * 2 + 1][kk];
            float b0 = Bs[kk][tx * 2], b1 = Bs[kk][tx * 2 + 1];
            acc00 += a0 * b0; acc01 += a0 * b1;
            acc10 += a1 * b0; acc11 += a1 * b1;
        }
        __syncthreads();
    }
    C[(size_t)(row0 + ty * 2)     * N + col0 + tx * 2]     = acc00;
    C[(size_t)(row0 + ty * 2)     * N + col0 + tx * 2 + 1] = acc01;
    C[(size_t)(row0 + ty * 2 + 1) * N + col0 + tx * 2]     = acc10;
    C[(size_t)(row0 + ty * 2 + 1) * N + col0 + tx * 2 + 1] = acc11;
}

// ---------------- n_valid = sum(mask) ----------------
__global__ void nvalid_kernel(const float* __restrict__ mask, float* __restrict__ nv) {
    __shared__ float red[256];
    int tid = threadIdx.x;
    red[tid] = mask[tid] + mask[tid + 256] + mask[tid + 512] + mask[tid + 768];
    __syncthreads();
    for (int off = 128; off; off >>= 1) { if (tid < off) red[tid] += red[tid + off]; __syncthreads(); }
    if (tid == 0) nv[0] = red[0];
}

// ---------------- Fused attention: one block per (n, h) row ----------------
// Q,K,V in (N, D) layout with head h at cols [h*32, h*32+32).
__global__ void attn_kernel(const float* __restrict__ Q, const float* __restrict__ Kb,
                            const float* __restrict__ V, const int* __restrict__ pos_bins,
                            const float* __restrict__ pos_w, const float* __restrict__ mask,
                            float* __restrict__ att) {
    int n = blockIdx.x, h = blockIdx.y;
    int tid = threadIdx.x;
    __shared__ float qrow[DHEAD];
    __shared__ float s[NTOK];
    __shared__ float red[256];
    if (tid < DHEAD) qrow[tid] = Q[(size_t)n * DMODEL + h * DHEAD + tid];
    __syncthreads();
    const float scale = 0.17677669529663687f; // 1/sqrt(32)
    for (int m = tid; m < NTOK; m += 256) {
        float acc = 0.f;
        const float* kr = &Kb[(size_t)m * DMODEL + h * DHEAD];
        #pragma unroll
        for (int d = 0; d < DHEAD; d++) acc += qrow[d] * kr[d];
        float bias = pos_w[pos_bins[(size_t)n * NTOK + m] * NHEAD + h];
        float v = acc * scale + bias;
        if (!(mask[m] > 0.f)) v = NEGV;
        s[m] = v;
    }
    __syncthreads();
    float mx = -INFINITY;
    for (int m = tid; m < NTOK; m += 256) mx = fmaxf(mx, s[m]);
    red[tid] = mx; __syncthreads();
    for (int off = 128; off; off >>= 1) { if (tid < off) red[tid] = fmaxf(red[tid], red[tid + off]); __syncthreads(); }
    mx = red[0];
    __syncthreads();
    float sum = 0.f;
    for (int m = tid; m < NTOK; m += 256) { float p = expf(s[m] - mx); s[m] = p; sum += p; }
    red[tid] = sum; __syncthreads();
    for (int off = 128; off; off >>= 1) { if (tid < off) red[tid] += red[tid + off]; __syncthreads(); }
    float inv = 1.f / red[0];
    __syncthreads();
    // PV: d = tid&31, 8 m-groups
    int d = tid & 31, grp = tid >> 5;
    float acc = 0.f;
    for (int m = grp; m < NTOK; m += 8) acc += s[m] * V[(size_t)m * DMODEL + h * DHEAD + d];
    red[tid] = acc; __syncthreads();
    if (grp == 0) {
        float a = 0.f;
        #pragma unroll
        for (int j = 0; j < 8; j++) a += red[j * 32 + d];
        att[(size_t)n * DMODEL + h * DHEAD + d] = a * inv;
    }
}

// ---------------- elementwise: h1 = h + sigmoid(G) * t1 * mask[n] ----------------
__global__ void mha_res_kernel(const float* __restrict__ h, const float* __restrict__ G,
                               const float* __restrict__ t1, const float* __restrict__ mask,
                               float* __restrict__ h1) {
    int i = blockIdx.x * 256 + threadIdx.x;
    float mk = mask[i >> 9];
    float sg = 1.f / (1.f + expf(-G[i]));
    h1[i] = h[i] + sg * t1[i] * mk;
}

// ---------------- elementwise: ff1 = silu(ff1) * ff3 ----------------
__global__ void silu_mul_kernel(float* __restrict__ ff1, const float* __restrict__ ff3) {
    int i = blockIdx.x * 256 + threadIdx.x;
    float x = ff1[i];
    float s = x / (1.f + expf(-x));
    ff1[i] = s * ff3[i];
}

// ---------------- elementwise: out = h1 + t1 * mask[n] ----------------
__global__ void ffn_res_kernel(const float* __restrict__ h1, const float* __restrict__ t1,
                               const float* __restrict__ mask, float* __restrict__ out) {
    int i = blockIdx.x * 256 + threadIdx.x;
    out[i] = h1[i] + t1[i] * mask[i >> 9];
}

// ---------------- normalize 32-vectors of Qs and Ks ----------------
__global__ void normvec_kernel(float* __restrict__ q, float* __restrict__ k) {
    int idx = blockIdx.x * 256 + threadIdx.x; // over N*H = 16384
    if (idx >= NTOK * NHEAD) return;
    int n = idx >> 4, h = idx & 15;
    float* p = &q[(size_t)n * DMODEL + h * DHEAD];
    float ss = 0.f;
    #pragma unroll
    for (int d = 0; d < DHEAD; d++) ss += p[d] * p[d];
    float inv = 1.f / fmaxf(sqrtf(ss), 1e-12f);
    #pragma unroll
    for (int d = 0; d < DHEAD; d++) p[d] *= inv;
    float* p2 = &k[(size_t)n * DMODEL + h * DHEAD];
    ss = 0.f;
    #pragma unroll
    for (int d = 0; d < DHEAD; d++) ss += p2[d] * p2[d];
    inv = 1.f / fmaxf(sqrtf(ss), 1e-12f);
    #pragma unroll
    for (int d = 0; d < DHEAD; d++) p2[d] *= inv;
}

// ---------------- logK matrix: S[h,n,m] = (r*sim + alpha)/eps, masked ----------------
__global__ void logk_kernel(const float* __restrict__ Qs, const float* __restrict__ Ks,
                            const float* __restrict__ mask, const float* __restrict__ r_h,
                            const float* __restrict__ alpha_h, const float* __restrict__ eps,
                            float* __restrict__ S) {
    int n = blockIdx.x, h = blockIdx.y;
    int tid = threadIdx.x;
    __shared__ float qrow[DHEAD];
    if (tid < DHEAD) qrow[tid] = Qs[(size_t)n * DMODEL + h * DHEAD + tid];
    __syncthreads();
    float r = r_h[h], al = alpha_h[h], ie = 1.f / eps[h];
    bool rowok = mask[n] > 0.f;
    float* out = &S[((size_t)h * NTOK + n) * NTOK];
    for (int m = tid; m < NTOK; m += 256) {
        float acc = 0.f;
        const float* kr = &Ks[(size_t)m * DMODEL + h * DHEAD];
        #pragma unroll
        for (int d = 0; d < DHEAD; d++) acc += qrow[d] * kr[d];
        float v = (r * acc + al) * ie;
        if (!rowok || !(mask[m] > 0.f)) v = NEGV;
        out[m] = v;
    }
}

// ---------------- sinkhorn f-update: f[h,n] = log_a[n] - LSE_m(S[h,n,m] + g[h,m]) --------
__global__ void sink_f_kernel(const float* __restrict__ S, const float* __restrict__ g,
                              const float* __restrict__ mask, const float* __restrict__ nv,
                              float* __restrict__ f) {
    int n = blockIdx.x, h = blockIdx.y;
    int tid = threadIdx.x;
    __shared__ float red[256];
    const float* row = &S[((size_t)h * NTOK + n) * NTOK];
    float vals[4];
    float mx = -INFINITY;
    #pragma unroll
    for (int i = 0; i < 4; i++) {
        int m = tid + i * 256;
        float v = row[m] + g[h * NTOK + m];
        vals[i] = v;
        mx = fmaxf(mx, v);
    }
    red[tid] = mx; __syncthreads();
    for (int off = 128; off; off >>= 1) { if (tid < off) red[tid] = fmaxf(red[tid], red[tid + off]); __syncthreads(); }
    mx = red[0];
    __syncthreads();
    float sum = 0.f;
    #pragma unroll
    for (int i = 0; i < 4; i++) sum += expf(vals[i] - mx);
    red[tid] = sum; __syncthreads();
    for (int off = 128; off; off >>= 1) { if (tid < off) red[tid] += red[tid + off]; __syncthreads(); }
    if (tid == 0) {
        float lse = mx + logf(red[0]);
        float la = (mask[n] > 0.f) ? -logf(nv[0]) : NEGV;
        f[h * NTOK + n] = la - lse;
    }
}

// ---------------- sinkhorn g-update: g[h,m] = log_a[m] - LSE_n(S[h,n,m] + f[h,n]) --------
// block = 256 thr = 64 cols x 4 row-groups; grid (N/64, H)
__global__ void sink_g_kernel(const float* __restrict__ S, const float* __restrict__ f,
                              const float* __restrict__ mask, const float* __restrict__ nv,
                              float* __restrict__ g) {
    int h = blockIdx.y;
    int m = blockIdx.x * 64 + (threadIdx.x & 63);
    int rg = threadIdx.x >> 6; // 0..3
    float M = -INFINITY, Ssum = 0.f;
    for (int n = rg; n < NTOK; n += 4) {
        float v = S[((size_t)h * NTOK + n) * NTOK + m] + f[h * NTOK + n];
        if (v > M) { Ssum = Ssum * expf(M - v) + 1.f; M = v; }
        else       { Ssum += expf(v - M); }
    }
    __shared__ float Ms[256], Ss[256];
    Ms[threadIdx.x] = M; Ss[threadIdx.x] = Ssum;
    __syncthreads();
    if (rg == 0) {
        int c = threadIdx.x;
        #pragma unroll
        for (int j = 1; j < 4; j++) {
            float M2 = Ms[j * 64 + c], S2 = Ss[j * 64 + c];
            if (M2 > M) { Ssum = Ssum * expf(M - M2) + S2; M = M2; }
            else        { Ssum += S2 * expf(M2 - M); }
        }
        float lse = M + logf(Ssum);
        float la = (mask[m] > 0.f) ? -logf(nv[0]) : NEGV;
        g[h * NTOK + m] = la - lse;
    }
}

// ---------------- transport: xc[h,n,c] = softmax_m(f+S+g) @ x_res[:,c] ----------------
__global__ void transport_kernel(const float* __restrict__ S, const float* __restrict__ f,
                                 const float* __restrict__ g, const float* __restrict__ x_res,
                                 float* __restrict__ xc) {
    int n = blockIdx.x, h = blockIdx.y;
    int tid = threadIdx.x;
    __shared__ float red[256];
    __shared__ float4 red4[256];
    const float* row = &S[((size_t)h * NTOK + n) * NTOK];
    float fr = f[h * NTOK + n];
    float vals[4];
    float mx = -INFINITY;
    #pragma unroll
    for (int i = 0; i < 4; i++) {
        int m = tid + i * 256;
        float v = fr + row[m] + g[h * NTOK + m];
        vals[i] = v;
        mx = fmaxf(mx, v);
    }
    red[tid] = mx; __syncthreads();
    for (int off = 128; off; off >>= 1) { if (tid < off) red[tid] = fmaxf(red[tid], red[tid + off]); __syncthreads(); }
    mx = red[0];
    __syncthreads();
    float sum = 0.f, a0 = 0.f, a1 = 0.f, a2 = 0.f;
    #pragma unroll
    for (int i = 0; i < 4; i++) {
        int m = tid + i * 256;
        float p = expf(vals[i] - mx);
        sum += p;
        a0 += p * x_res[m * 3 + 0];
        a1 += p * x_res[m * 3 + 1];
        a2 += p * x_res[m * 3 + 2];
    }
    red4[tid] = make_float4(sum, a0, a1, a2);
    __syncthreads();
    for (int off = 128; off; off >>= 1) {
        if (tid < off) {
            float4 o = red4[tid + off];
            red4[tid].x += o.x; red4[tid].y += o.y; red4[tid].z += o.z; red4[tid].w += o.w;
        }
        __syncthreads();
    }
    if (tid == 0) {
        float inv = 1.f / red4[0].x;
        xc[((size_t)h * NTOK + n) * 3 + 0] = red4[0].y * inv;
        xc[((size_t)h * NTOK + n) * 3 + 1] = red4[0].z * inv;
        xc[((size_t)h * NTOK + n) * 3 + 2] = red4[0].w * inv;
    }
}

// ---------------- final: gate=sigmoid(LN(h2)@wg+b); x_out = x_res + gate*disp*mask ------
__global__ void final_kernel(const float* __restrict__ h2, const float* __restrict__ x_res,
                             const float* __restrict__ mask, const float* __restrict__ gm,
                             const float* __restrict__ bt, const float* __restrict__ wg,
                             const float* __restrict__ wb, const float* __restrict__ lamraw,
                             const float* __restrict__ xc, float* __restrict__ xout) {
    int n = blockIdx.x;
    int tid = threadIdx.x;
    __shared__ float red[256];
    const float* row = h2 + (size_t)n * DMODEL;
    float a = row[tid], b = row[tid + 256];
    red[tid] = a + b;
    __syncthreads();
    for (int off = 128; off; off >>= 1) { if (tid < off) red[tid] += red[tid + off]; __syncthreads(); }
    float mu = red[0] * (1.0f / DMODEL);
    __syncthreads();
    float d0 = a - mu, d1 = b - mu;
    red[tid] = d0 * d0 + d1 * d1;
    __syncthreads();
    for (int off = 128; off; off >>= 1) { if (tid < off) red[tid] += red[tid + off]; __syncthreads(); }
    float rstd = rsqrtf(red[0] * (1.0f / DMODEL) + 1e-5f);
    __syncthreads();
    float t0 = (d0 * rstd * gm[tid] + bt[tid]) * wg[tid];
    float t1 = (d1 * rstd * gm[tid + 256] + bt[tid + 256]) * wg[tid + 256];
    red[tid] = t0 + t1;
    __syncthreads();
    for (int off = 128; off; off >>= 1) { if (tid < off) red[tid] += red[tid + off]; __syncthreads(); }
    if (tid == 0) {
        float gate = 1.f / (1.f + expf(-(red[0] + wb[0])));
        float mk = mask[n];
        #pragma unroll
        for (int c = 0; c < 3; c++) {
            float xr = x_res[n * 3 + c];
            float disp = 0.f;
            for (int h = 0; h < NHEAD; h++) {
                float lam = tanhf(lamraw[h]) * (1.f / NHEAD);
                disp += lam * (xc[((size_t)h * NTOK + n) * 3 + c] - xr);
            }
            xout[n * 3 + c] = xr + gate * disp * mk;
        }
    }
}

extern "C" void kernel_launch(void* const* d_in, const int* in_sizes, int n_in,
                              void* d_out, int out_size, void* d_ws, size_t ws_size,
                              hipStream_t stream) {
    const float* h          = (const float*)d_in[0];
    const float* x_res      = (const float*)d_in[1];
    const int*   pos_bins   = (const int*)d_in[2];
    const float* mask       = (const float*)d_in[3];
    const float* ln_mha_g   = (const float*)d_in[4];
    const float* ln_mha_b   = (const float*)d_in[5];
    const float* w_q        = (const float*)d_in[6];
    const float* w_k        = (const float*)d_in[7];
    const float* w_v        = (const float*)d_in[8];
    const float* w_g        = (const float*)d_in[9];
    const float* w_o        = (const float*)d_in[10];
    const float* pos_w      = (const float*)d_in[11];
    const float* ln_ff_g    = (const float*)d_in[12];
    const float* ln_ff_b    = (const float*)d_in[13];
    const float* sw_w1      = (const float*)d_in[14];
    const float* sw_w3      = (const float*)d_in[15];
    const float* sw_w2      = (const float*)d_in[16];
    const float* ln_sink_g  = (const float*)d_in[17];
    const float* ln_sink_b  = (const float*)d_in[18];
    const float* w_q_sink   = (const float*)d_in[19];
    const float* w_k_sink   = (const float*)d_in[20];
    const float* alpha_h    = (const float*)d_in[21];
    const float* r_h        = (const float*)d_in[22];
    const float* eps        = (const float*)d_in[23];
    const float* ln_gate_g  = (const float*)d_in[24];
    const float* ln_gate_b  = (const float*)d_in[25];
    const float* w_gate_w   = (const float*)d_in[26];
    const float* w_gate_b   = (const float*)d_in[27];
    const float* lambda_raw = (const float*)d_in[28];
    float* out = (float*)d_out;

    // workspace layout (floats)
    const size_t ND = (size_t)NTOK * DMODEL;        // 524288
    const size_t NF = (size_t)NTOK * DFF;           // 2097152
    const size_t NS = (size_t)NHEAD * NTOK * NTOK;  // 16777216
    float* w  = (float*)d_ws;
    float* hn  = w;            // ND
    float* q   = hn + ND;      // ND
    float* k   = q + ND;       // ND
    float* v   = k + ND;       // ND
    float* gp  = v + ND;       // ND
    float* att = gp + ND;      // ND
    float* t1  = att + ND;     // ND
    float* h1  = t1 + ND;      // ND
    float* ff1 = h1 + ND;      // NF
    float* ff3 = ff1 + NF;     // NF
    float* S   = ff3 + NF;     // NS
    float* fv  = S + NS;       // NHEAD*NTOK
    float* gv  = fv + NHEAD * NTOK;
    float* xc  = gv + NHEAD * NTOK;   // NHEAD*NTOK*3
    float* nv  = xc + (size_t)NHEAD * NTOK * 3;

    dim3 blk2(16, 16);
    dim3 gD(DMODEL / 32, NTOK / 32);   // 512-col GEMMs
    dim3 gF(DFF / 32, NTOK / 32);      // 2048-col GEMMs

    nvalid_kernel<<<1, 256, 0, stream>>>(mask, nv);

    // ---- MHA ----
    ln_kernel<<<NTOK, 256, 0, stream>>>(h, ln_mha_g, ln_mha_b, hn);
    gemm_kernel<<<gD, blk2, 0, stream>>>(hn, w_q, q, NTOK, DMODEL, DMODEL);
    gemm_kernel<<<gD, blk2, 0, stream>>>(hn, w_k, k, NTOK, DMODEL, DMODEL);
    gemm_kernel<<<gD, blk2, 0, stream>>>(hn, w_v, v, NTOK, DMODEL, DMODEL);
    gemm_kernel<<<gD, blk2, 0, stream>>>(hn, w_g, gp, NTOK, DMODEL, DMODEL);
    attn_kernel<<<dim3(NTOK, NHEAD), 256, 0, stream>>>(q, k, v, pos_bins, pos_w, mask, att);
    gemm_kernel<<<gD, blk2, 0, stream>>>(att, w_o, t1, NTOK, DMODEL, DMODEL);
    mha_res_kernel<<<ND / 256, 256, 0, stream>>>(h, gp, t1, mask, h1);

    // ---- FFN ----
    ln_kernel<<<NTOK, 256, 0, stream>>>(h1, ln_ff_g, ln_ff_b, hn);
    gemm_kernel<<<gF, blk2, 0, stream>>>(hn, sw_w1, ff1, NTOK, DMODEL, DFF);
    gemm_kernel<<<gF, blk2, 0, stream>>>(hn, sw_w3, ff3, NTOK, DMODEL, DFF);
    silu_mul_kernel<<<NF / 256, 256, 0, stream>>>(ff1, ff3);
    gemm_kernel<<<gD, blk2, 0, stream>>>(ff1, sw_w2, t1, NTOK, DFF, DMODEL);
    ffn_res_kernel<<<ND / 256, 256, 0, stream>>>(h1, t1, mask, out);  // h2 -> out[0:ND]

    // ---- Sinkhorn ----
    ln_kernel<<<NTOK, 256, 0, stream>>>(out, ln_sink_g, ln_sink_b, hn);
    gemm_kernel<<<gD, blk2, 0, stream>>>(hn, w_q_sink, q, NTOK, DMODEL, DMODEL);
    gemm_kernel<<<gD, blk2, 0, stream>>>(hn, w_k_sink, k, NTOK, DMODEL, DMODEL);
    normvec_kernel<<<(NTOK * NHEAD) / 256, 256, 0, stream>>>(q, k);
    logk_kernel<<<dim3(NTOK, NHEAD), 256, 0, stream>>>(q, k, mask, r_h, alpha_h, eps, S);

    hipMemsetAsync(gv, 0, NHEAD * NTOK * sizeof(float), stream);
    for (int it = 0; it < KIT; it++) {
        sink_f_kernel<<<dim3(NTOK, NHEAD), 256, 0, stream>>>(S, gv, mask, nv, fv);
        sink_g_kernel<<<dim3(NTOK / 64, NHEAD), 256, 0, stream>>>(S, fv, mask, nv, gv);
    }
    transport_kernel<<<dim3(NTOK, NHEAD), 256, 0, stream>>>(S, fv, gv, x_res, xc);

    final_kernel<<<NTOK, 256, 0, stream>>>(out, x_res, mask, ln_gate_g, ln_gate_b,
                                           w_gate_w, w_gate_b, lambda_raw, xc, out + ND);
}

// Round 2
// 1271.746 us; speedup vs baseline: 2.9696x; 2.9696x over previous
//
#include <hip/hip_runtime.h>
#include <hip/hip_bf16.h>
#include <hip/hip_fp16.h>
#include <math.h>

#define NTOK 1024
#define DMODEL 512
#define NHEAD 16
#define DHEAD 32
#define DFF 2048
#define NBINS 68
#define KIT 20
#define NEGV (-1e9f)
#define NEGH (-30000.0f)   // masked logit sentinel for fp16 S storage

typedef __attribute__((ext_vector_type(8))) short bf16x8;
typedef __attribute__((ext_vector_type(4))) float f32x4;
typedef __attribute__((ext_vector_type(8))) unsigned short u16x8;

__device__ inline unsigned short f2bf(float f) {
    unsigned int u = __float_as_uint(f);
    unsigned int r = (u + 0x7fff + ((u >> 16) & 1)) >> 16;
    return (unsigned short)r;
}

// ---- block-wide reductions (256 threads = 4 waves), red4 = 4-float shared scratch ----
__device__ inline float block_max256(float v, float* red4) {
    #pragma unroll
    for (int s = 32; s; s >>= 1) v = fmaxf(v, __shfl_xor(v, s, 64));
    if ((threadIdx.x & 63) == 0) red4[threadIdx.x >> 6] = v;
    __syncthreads();
    v = fmaxf(fmaxf(red4[0], red4[1]), fmaxf(red4[2], red4[3]));
    __syncthreads();
    return v;
}
__device__ inline float block_sum256(float v, float* red4) {
    #pragma unroll
    for (int s = 32; s; s >>= 1) v += __shfl_xor(v, s, 64);
    if ((threadIdx.x & 63) == 0) red4[threadIdx.x >> 6] = v;
    __syncthreads();
    v = red4[0] + red4[1] + red4[2] + red4[3];
    __syncthreads();
    return v;
}

// ---------------- LayerNorm -> bf16 out ----------------
__global__ void ln_bf16_kernel(const float* __restrict__ x, const float* __restrict__ gm,
                               const float* __restrict__ bt, unsigned short* __restrict__ out) {
    int n = blockIdx.x;
    int tid = threadIdx.x;
    __shared__ float red[256];
    const float* row = x + (size_t)n * DMODEL;
    float a = row[tid], b = row[tid + 256];
    red[tid] = a + b;
    __syncthreads();
    for (int off = 128; off; off >>= 1) { if (tid < off) red[tid] += red[tid + off]; __syncthreads(); }
    float mu = red[0] * (1.0f / DMODEL);
    __syncthreads();
    float d0 = a - mu, d1 = b - mu;
    red[tid] = d0 * d0 + d1 * d1;
    __syncthreads();
    for (int off = 128; off; off >>= 1) { if (tid < off) red[tid] += red[tid + off]; __syncthreads(); }
    float rstd = rsqrtf(red[0] * (1.0f / DMODEL) + 1e-5f);
    out[(size_t)n * DMODEL + tid]       = f2bf(d0 * rstd * gm[tid] + bt[tid]);
    out[(size_t)n * DMODEL + tid + 256] = f2bf(d1 * rstd * gm[tid + 256] + bt[tid + 256]);
}

// ---------------- weight transpose + cast: Wt[n][k] = bf16(W[k][n]) ----------------
__global__ void wtrans_kernel(const float* __restrict__ W, unsigned short* __restrict__ Wt,
                              int K, int N) {
    __shared__ float T[32][33];
    int k0 = blockIdx.y * 32, n0 = blockIdx.x * 32, tid = threadIdx.x;
    int r = tid >> 3, c0 = (tid & 7) * 4;
    float4 v = *(const float4*)&W[(size_t)(k0 + r) * N + n0 + c0];
    T[r][c0] = v.x; T[r][c0 + 1] = v.y; T[r][c0 + 2] = v.z; T[r][c0 + 3] = v.w;
    __syncthreads();
    ushort4 o;
    o.x = f2bf(T[c0][r]); o.y = f2bf(T[c0 + 1][r]);
    o.z = f2bf(T[c0 + 2][r]); o.w = f2bf(T[c0 + 3][r]);
    *(ushort4*)&Wt[(size_t)(n0 + r) * K + k0 + c0] = o;
}

// ---------------- n_valid ----------------
__global__ void nvalid_kernel(const float* __restrict__ mask, float* __restrict__ nv) {
    __shared__ float red[256];
    int tid = threadIdx.x;
    red[tid] = mask[tid] + mask[tid + 256] + mask[tid + 512] + mask[tid + 768];
    __syncthreads();
    for (int off = 128; off; off >>= 1) { if (tid < off) red[tid] += red[tid + off]; __syncthreads(); }
    if (tid == 0) nv[0] = red[0];
}

// ---------------- MFMA GEMM: C[M][N] = A[M][K] @ Bt[N][K]^T (bf16 in, f32 acc) ----------
// 128x128 tile, BK=64, 256 thr = 4 waves (2x2), 4x4 16x16x32 frags/wave.
// MODE 0: store f32 C.  MODE 1: v += alpha[h]/eps[h]; mask row/col -> NEGH; store fp16.
template<int MODE>
__global__ __launch_bounds__(256)
void mfma_gemm(const unsigned short* __restrict__ A, const unsigned short* __restrict__ Bt,
               float* __restrict__ C, __half* __restrict__ Ch,
               int N, int K, long sA, long sB, long sC,
               const float* __restrict__ alpha, const float* __restrict__ epsv,
               const float* __restrict__ mask) {
    __shared__ unsigned short As[128 * 64];
    __shared__ unsigned short Bs[128 * 64];
    const int h = blockIdx.z;
    A += (size_t)h * sA; Bt += (size_t)h * sB;
    const int tid = threadIdx.x;
    const int lane = tid & 63, wid = tid >> 6;
    const int wr = wid >> 1, wc = wid & 1;
    const int lr = lane & 15, kg = lane >> 4;
    const int row0 = blockIdx.y * 128, col0 = blockIdx.x * 128;
    f32x4 acc[4][4];
    #pragma unroll
    for (int i = 0; i < 4; i++)
        #pragma unroll
        for (int j = 0; j < 4; j++) acc[i][j] = (f32x4){0.f, 0.f, 0.f, 0.f};

    for (int k0 = 0; k0 < K; k0 += 64) {
        #pragma unroll
        for (int i = 0; i < 4; i++) {           // stage 128x64 A and Bt tiles (swizzled)
            int cid = tid + i * 256;
            int r = cid >> 3, sl = cid & 7;
            u16x8 va = *(const u16x8*)&A[(size_t)(row0 + r) * K + k0 + sl * 8];
            u16x8 vb = *(const u16x8*)&Bt[(size_t)(col0 + r) * K + k0 + sl * 8];
            *(u16x8*)&As[r * 64 + ((sl ^ (r & 7)) * 8)] = va;
            *(u16x8*)&Bs[r * 64 + ((sl ^ (r & 7)) * 8)] = vb;
        }
        __syncthreads();
        #pragma unroll
        for (int ks = 0; ks < 2; ks++) {
            bf16x8 af[4], bfr[4];
            #pragma unroll
            for (int f = 0; f < 4; f++) {
                int ra = wr * 64 + f * 16 + lr;
                af[f] = *(const bf16x8*)&As[ra * 64 + (((ks * 4 + kg) ^ (ra & 7)) * 8)];
                int rb = wc * 64 + f * 16 + lr;
                bfr[f] = *(const bf16x8*)&Bs[rb * 64 + (((ks * 4 + kg) ^ (rb & 7)) * 8)];
            }
            #pragma unroll
            for (int i = 0; i < 4; i++)
                #pragma unroll
                for (int j = 0; j < 4; j++)
                    acc[i][j] = __builtin_amdgcn_mfma_f32_16x16x32_bf16(af[i], bfr[j], acc[i][j], 0, 0, 0);
        }
        __syncthreads();
    }
    float beta = 0.f;
    if (MODE == 1) beta = alpha[h] / epsv[h];
    #pragma unroll
    for (int i = 0; i < 4; i++) {
        int row = row0 + wr * 64 + i * 16 + kg * 4;
        #pragma unroll
        for (int j = 0; j < 4; j++) {
            int col = col0 + wc * 64 + j * 16 + lr;
            #pragma unroll
            for (int e = 0; e < 4; e++) {
                float v = acc[i][j][e];
                if (MODE == 0) {
                    C[(size_t)h * sC + (size_t)(row + e) * N + col] = v;
                } else {
                    v += beta;
                    if (!(mask[row + e] > 0.f) || !(mask[col] > 0.f)) v = NEGH;
                    Ch[(size_t)h * sC + (size_t)(row + e) * N + col] = __float2half(v);
                }
            }
        }
    }
}

// ---------------- pad-cast Q,K per head into [H][N][64] bf16 (zero-padded K-dim) --------
__global__ void qkpad_kernel(const float* __restrict__ src, int stride, int qoff, int koff,
                             const float* __restrict__ rh, const float* __restrict__ ev,
                             unsigned short* __restrict__ Qp, unsigned short* __restrict__ Kp) {
    int idx = blockIdx.x * 256 + threadIdx.x;     // over 16*1024*64
    int k = idx & 63, n = (idx >> 6) & 1023, h = idx >> 16;
    float s = rh ? rh[h] / ev[h] : 0.17677669529663687f;
    unsigned short qv = 0, kv = 0;
    if (k < 32) {
        qv = f2bf(src[(size_t)n * stride + qoff + h * 32 + k] * s);
        kv = f2bf(src[(size_t)n * stride + koff + h * 32 + k]);
    }
    Qp[idx] = qv; Kp[idx] = kv;
}

// ---------------- attention: bias + mask + softmax (in place on f32 S rows) ----------------
__global__ void bias_softmax_kernel(float* __restrict__ S, const int* __restrict__ pos_bins,
                                    const float* __restrict__ pos_w, const float* __restrict__ mask) {
    int n = blockIdx.x, h = blockIdx.y, tid = threadIdx.x;
    __shared__ float red4[4];
    float* row = S + ((size_t)h * NTOK + n) * NTOK;
    float4 s4 = ((const float4*)row)[tid];
    int4 b4 = ((const int4*)(pos_bins + (size_t)n * NTOK))[tid];
    float4 m4 = ((const float4*)mask)[tid];
    float v0 = (m4.x > 0.f) ? s4.x + pos_w[b4.x * NHEAD + h] : NEGV;
    float v1 = (m4.y > 0.f) ? s4.y + pos_w[b4.y * NHEAD + h] : NEGV;
    float v2 = (m4.z > 0.f) ? s4.z + pos_w[b4.z * NHEAD + h] : NEGV;
    float v3 = (m4.w > 0.f) ? s4.w + pos_w[b4.w * NHEAD + h] : NEGV;
    float mx = block_max256(fmaxf(fmaxf(v0, v1), fmaxf(v2, v3)), red4);
    float p0 = __expf(v0 - mx), p1 = __expf(v1 - mx), p2 = __expf(v2 - mx), p3 = __expf(v3 - mx);
    float inv = 1.f / block_sum256(p0 + p1 + p2 + p3, red4);
    ((float4*)row)[tid] = make_float4(p0 * inv, p1 * inv, p2 * inv, p3 * inv);
}

// ---------------- PV: att[n][h*32+d] = sum_m P[h][n][m] * V[m][h*32+d], bf16 out --------
__global__ void pv_kernel(const float* __restrict__ P, const float* __restrict__ qkvg,
                          unsigned short* __restrict__ attb) {
    int n = blockIdx.x, h = blockIdx.y, tid = threadIdx.x;
    __shared__ float s[NTOK];
    __shared__ float red[256];
    ((float4*)s)[tid] = ((const float4*)(P + ((size_t)h * NTOK + n) * NTOK))[tid];
    __syncthreads();
    int d = tid & 31, grp = tid >> 5;
    const float* V = qkvg + 1024 + h * 32 + d;   // V block at cols [1024,1536)
    float acc = 0.f;
    for (int m = grp; m < NTOK; m += 8) acc += s[m] * V[(size_t)m * 2048];
    red[tid] = acc; __syncthreads();
    if (tid < 128) red[tid] += red[tid + 128]; __syncthreads();
    if (tid < 64)  red[tid] += red[tid + 64];  __syncthreads();
    if (tid < 32)  attb[(size_t)n * DMODEL + h * 32 + tid] = f2bf(red[tid] + red[tid + 32]);
}

// ---------------- h1 = h + sigmoid(G)*t1*mask ; G at qkvg cols [1536,2048) ----------------
__global__ void mha_res_kernel(const float* __restrict__ h, const float* __restrict__ qkvg,
                               const float* __restrict__ t1, const float* __restrict__ mask,
                               float* __restrict__ h1) {
    int i = blockIdx.x * 256 + threadIdx.x;
    int n = i >> 9, d = i & 511;
    float gval = qkvg[(size_t)n * 2048 + 1536 + d];
    float sg = 1.f / (1.f + __expf(-gval));
    h1[i] = h[i] + sg * t1[i] * mask[n];
}

// ---------------- silu(ff1)*ff3 from fused [1024][4096] -> bf16 [1024][2048] ----------------
__global__ void silu_mul_kernel(const float* __restrict__ ff, unsigned short* __restrict__ ffb) {
    int i = blockIdx.x * 256 + threadIdx.x;   // over 1024*2048
    int n = i >> 11, c = i & 2047;
    float x = ff[(size_t)n * 4096 + c], y = ff[(size_t)n * 4096 + 2048 + c];
    ffb[i] = f2bf(x / (1.f + __expf(-x)) * y);
}

// ---------------- out = h1 + t1*mask ----------------
__global__ void ffn_res_kernel(const float* __restrict__ h1, const float* __restrict__ t1,
                               const float* __restrict__ mask, float* __restrict__ out) {
    int i = blockIdx.x * 256 + threadIdx.x;
    out[i] = h1[i] + t1[i] * mask[i >> 9];
}

// ---------------- normalize per-head 32-vectors in fused qs|ks [1024][1024] ----------------
__global__ void normvec_kernel(float* __restrict__ qsks) {
    int idx = blockIdx.x * 256 + threadIdx.x;   // 16384
    int n = idx >> 4, h = idx & 15;
    float* p = &qsks[(size_t)n * 1024 + h * 32];
    float ss = 0.f;
    #pragma unroll
    for (int d = 0; d < 32; d++) ss += p[d] * p[d];
    float inv = 1.f / fmaxf(sqrtf(ss), 1e-12f);
    #pragma unroll
    for (int d = 0; d < 32; d++) p[d] *= inv;
    float* p2 = &qsks[(size_t)n * 1024 + 512 + h * 32];
    ss = 0.f;
    #pragma unroll
    for (int d = 0; d < 32; d++) ss += p2[d] * p2[d];
    inv = 1.f / fmaxf(sqrtf(ss), 1e-12f);
    #pragma unroll
    for (int d = 0; d < 32; d++) p2[d] *= inv;
}

// ---------------- sinkhorn pass: out[h,i] = la_i - LSE_j((float)Sb[h,i,j] + dual[h,j]) ----
__global__ void sink_pass_kernel(const __half* __restrict__ Sb, const float* __restrict__ dual,
                                 const float* __restrict__ mask, const float* __restrict__ nv,
                                 float* __restrict__ outv) {
    int i = blockIdx.x, h = blockIdx.y, tid = threadIdx.x;
    __shared__ float red4[4];
    const __half2* r2 = (const __half2*)(Sb + ((size_t)h * NTOK + i) * NTOK);
    __half2 p0 = r2[tid * 2], p1 = r2[tid * 2 + 1];
    float2 fa = __half22float2(p0), fb = __half22float2(p1);
    float4 d4 = ((const float4*)(dual + (size_t)h * NTOK))[tid];
    float v0 = fa.x + d4.x, v1 = fa.y + d4.y, v2 = fb.x + d4.z, v3 = fb.y + d4.w;
    float mx = block_max256(fmaxf(fmaxf(v0, v1), fmaxf(v2, v3)), red4);
    float sum = __expf(v0 - mx) + __expf(v1 - mx) + __expf(v2 - mx) + __expf(v3 - mx);
    sum = block_sum256(sum, red4);
    if (tid == 0) {
        float la = (mask[i] > 0.f) ? -__logf(nv[0]) : NEGV;
        outv[(size_t)h * NTOK + i] = la - (mx + __logf(sum));
    }
}

// ---------------- transport: xc[h,n,:] = softmax_m(f + S + g) @ x_res ----------------
__global__ void transport_kernel(const __half* __restrict__ Sb, const float* __restrict__ f,
                                 const float* __restrict__ g, const float* __restrict__ x_res,
                                 float* __restrict__ xc) {
    int n = blockIdx.x, h = blockIdx.y, tid = threadIdx.x;
    __shared__ float red4[4];
    const __half2* r2 = (const __half2*)(Sb + ((size_t)h * NTOK + n) * NTOK);
    __half2 p0 = r2[tid * 2], p1 = r2[tid * 2 + 1];
    float2 fa = __half22float2(p0), fb = __half22float2(p1);
    float4 d4 = ((const float4*)(g + (size_t)h * NTOK))[tid];
    float fr = f[(size_t)h * NTOK + n];
    float v0 = fr + fa.x + d4.x, v1 = fr + fa.y + d4.y;
    float v2 = fr + fb.x + d4.z, v3 = fr + fb.y + d4.w;
    float mx = block_max256(fmaxf(fmaxf(v0, v1), fmaxf(v2, v3)), red4);
    float e0 = __expf(v0 - mx), e1 = __expf(v1 - mx), e2 = __expf(v2 - mx), e3 = __expf(v3 - mx);
    int m = tid * 4;
    float sum = block_sum256(e0 + e1 + e2 + e3, red4);
    float a0 = block_sum256(e0 * x_res[m * 3] + e1 * x_res[m * 3 + 3] + e2 * x_res[m * 3 + 6] + e3 * x_res[m * 3 + 9], red4);
    float a1 = block_sum256(e0 * x_res[m * 3 + 1] + e1 * x_res[m * 3 + 4] + e2 * x_res[m * 3 + 7] + e3 * x_res[m * 3 + 10], red4);
    float a2 = block_sum256(e0 * x_res[m * 3 + 2] + e1 * x_res[m * 3 + 5] + e2 * x_res[m * 3 + 8] + e3 * x_res[m * 3 + 11], red4);
    if (tid == 0) {
        float inv = 1.f / sum;
        xc[((size_t)h * NTOK + n) * 3 + 0] = a0 * inv;
        xc[((size_t)h * NTOK + n) * 3 + 1] = a1 * inv;
        xc[((size_t)h * NTOK + n) * 3 + 2] = a2 * inv;
    }
}

// ---------------- final: gate = sigmoid(LN(h2)@wg + b); x_out = x_res + gate*disp*mask ----
__global__ void final_kernel(const float* __restrict__ h2, const float* __restrict__ x_res,
                             const float* __restrict__ mask, const float* __restrict__ gm,
                             const float* __restrict__ bt, const float* __restrict__ wg,
                             const float* __restrict__ wb, const float* __restrict__ lamraw,
                             const float* __restrict__ xc, float* __restrict__ xout) {
    int n = blockIdx.x;
    int tid = threadIdx.x;
    __shared__ float red[256];
    const float* row = h2 + (size_t)n * DMODEL;
    float a = row[tid], b = row[tid + 256];
    red[tid] = a + b;
    __syncthreads();
    for (int off = 128; off; off >>= 1) { if (tid < off) red[tid] += red[tid + off]; __syncthreads(); }
    float mu = red[0] * (1.0f / DMODEL);
    __syncthreads();
    float d0 = a - mu, d1 = b - mu;
    red[tid] = d0 * d0 + d1 * d1;
    __syncthreads();
    for (int off = 128; off; off >>= 1) { if (tid < off) red[tid] += red[tid + off]; __syncthreads(); }
    float rstd = rsqrtf(red[0] * (1.0f / DMODEL) + 1e-5f);
    __syncthreads();
    float t0 = (d0 * rstd * gm[tid] + bt[tid]) * wg[tid];
    float t1 = (d1 * rstd * gm[tid + 256] + bt[tid + 256]) * wg[tid + 256];
    red[tid] = t0 + t1;
    __syncthreads();
    for (int off = 128; off; off >>= 1) { if (tid < off) red[tid] += red[tid + off]; __syncthreads(); }
    if (tid == 0) {
        float gate = 1.f / (1.f + expf(-(red[0] + wb[0])));
        float mk = mask[n];
        #pragma unroll
        for (int c = 0; c < 3; c++) {
            float xr = x_res[n * 3 + c];
            float disp = 0.f;
            for (int h = 0; h < NHEAD; h++) {
                float lam = tanhf(lamraw[h]) * (1.f / NHEAD);
                disp += lam * (xc[((size_t)h * NTOK + n) * 3 + c] - xr);
            }
            xout[n * 3 + c] = xr + gate * disp * mk;
        }
    }
}

extern "C" void kernel_launch(void* const* d_in, const int* in_sizes, int n_in,
                              void* d_out, int out_size, void* d_ws, size_t ws_size,
                              hipStream_t stream) {
    const float* h          = (const float*)d_in[0];
    const float* x_res      = (const float*)d_in[1];
    const int*   pos_bins   = (const int*)d_in[2];
    const float* mask       = (const float*)d_in[3];
    const float* ln_mha_g   = (const float*)d_in[4];
    const float* ln_mha_b   = (const float*)d_in[5];
    const float* w_q        = (const float*)d_in[6];
    const float* w_k        = (const float*)d_in[7];
    const float* w_v        = (const float*)d_in[8];
    const float* w_g        = (const float*)d_in[9];
    const float* w_o        = (const float*)d_in[10];
    const float* pos_w      = (const float*)d_in[11];
    const float* ln_ff_g    = (const float*)d_in[12];
    const float* ln_ff_b    = (const float*)d_in[13];
    const float* sw_w1      = (const float*)d_in[14];
    const float* sw_w3      = (const float*)d_in[15];
    const float* sw_w2      = (const float*)d_in[16];
    const float* ln_sink_g  = (const float*)d_in[17];
    const float* ln_sink_b  = (const float*)d_in[18];
    const float* w_q_sink   = (const float*)d_in[19];
    const float* w_k_sink   = (const float*)d_in[20];
    const float* alpha_h    = (const float*)d_in[21];
    const float* r_h        = (const float*)d_in[22];
    const float* eps        = (const float*)d_in[23];
    const float* ln_gate_g  = (const float*)d_in[24];
    const float* ln_gate_b  = (const float*)d_in[25];
    const float* w_gate_w   = (const float*)d_in[26];
    const float* w_gate_b   = (const float*)d_in[27];
    const float* lambda_raw = (const float*)d_in[28];
    float* out = (float*)d_out;
    const size_t ND = (size_t)NTOK * DMODEL;

    // ---- workspace bump allocator (256B aligned) ----
    char* Wp = (char*)d_ws;
    auto alloc = [&](size_t bytes) { char* p = Wp; Wp += (bytes + 255) & ~(size_t)255; return p; };
    unsigned short* wt_qkvg = (unsigned short*)alloc((size_t)2048 * 512 * 2);
    unsigned short* wt_o    = (unsigned short*)alloc((size_t)512 * 512 * 2);
    unsigned short* wt_13   = (unsigned short*)alloc((size_t)4096 * 512 * 2);
    unsigned short* wt_2    = (unsigned short*)alloc((size_t)512 * 2048 * 2);
    unsigned short* wt_qsks = (unsigned short*)alloc((size_t)1024 * 512 * 2);
    unsigned short* hnb     = (unsigned short*)alloc(ND * 2);
    float*          qkvg    = (float*)alloc((size_t)1024 * 2048 * 4);     // also reused as qs|ks f32
    unsigned short* attb    = (unsigned short*)alloc(ND * 2);
    float*          t1      = (float*)alloc(ND * 4);
    float*          h1      = (float*)alloc(ND * 4);
    unsigned short* ffb     = (unsigned short*)alloc((size_t)1024 * 2048 * 2);
    unsigned short* Qp      = (unsigned short*)alloc((size_t)16 * 1024 * 64 * 2);
    unsigned short* Kp      = (unsigned short*)alloc((size_t)16 * 1024 * 64 * 2);
    char*           R       = alloc((size_t)64 * 1024 * 1024);            // big shared region
    float*          fv      = (float*)alloc((size_t)16 * 1024 * 4);
    float*          gv      = (float*)alloc((size_t)16 * 1024 * 4);
    float*          xc      = (float*)alloc((size_t)16 * 1024 * 3 * 4);
    float*          nv      = (float*)alloc(256);

    float*  Sraw  = (float*)R;                                  // attention scores/P (64MB)
    float*  ff13  = (float*)R;                                  // FFN fused out (16MB)
    __half* Sh    = (__half*)R;                                 // sinkhorn S fp16 (32MB)
    __half* Sth   = (__half*)(R + (size_t)32 * 1024 * 1024);    // sinkhorn S^T fp16 (32MB)
    float*  qsks  = qkvg;

    nvalid_kernel<<<1, 256, 0, stream>>>(mask, nv);

    // ---- weight prep (order-independent) ----
    wtrans_kernel<<<dim3(512/32, 512/32), 256, 0, stream>>>(w_q, wt_qkvg,                512, 512);
    wtrans_kernel<<<dim3(512/32, 512/32), 256, 0, stream>>>(w_k, wt_qkvg + 512*512,      512, 512);
    wtrans_kernel<<<dim3(512/32, 512/32), 256, 0, stream>>>(w_v, wt_qkvg + 2*512*512,    512, 512);
    wtrans_kernel<<<dim3(512/32, 512/32), 256, 0, stream>>>(w_g, wt_qkvg + 3*512*512,    512, 512);
    wtrans_kernel<<<dim3(512/32, 512/32), 256, 0, stream>>>(w_o, wt_o,                   512, 512);
    wtrans_kernel<<<dim3(2048/32, 512/32), 256, 0, stream>>>(sw_w1, wt_13,               512, 2048);
    wtrans_kernel<<<dim3(2048/32, 512/32), 256, 0, stream>>>(sw_w3, wt_13 + 2048*512,    512, 2048);
    wtrans_kernel<<<dim3(512/32, 2048/32), 256, 0, stream>>>(sw_w2, wt_2,                2048, 512);
    wtrans_kernel<<<dim3(512/32, 512/32), 256, 0, stream>>>(w_q_sink, wt_qsks,           512, 512);
    wtrans_kernel<<<dim3(512/32, 512/32), 256, 0, stream>>>(w_k_sink, wt_qsks + 512*512, 512, 512);

    // ---- MHA ----
    ln_bf16_kernel<<<NTOK, 256, 0, stream>>>(h, ln_mha_g, ln_mha_b, hnb);
    mfma_gemm<0><<<dim3(16, 8, 1), 256, 0, stream>>>(hnb, wt_qkvg, qkvg, nullptr,
        2048, 512, 0, 0, 0, nullptr, nullptr, nullptr);
    qkpad_kernel<<<4096, 256, 0, stream>>>(qkvg, 2048, 0, 512, nullptr, nullptr, Qp, Kp);
    mfma_gemm<0><<<dim3(8, 8, 16), 256, 0, stream>>>(Qp, Kp, Sraw, nullptr,
        1024, 64, 65536, 65536, 1048576, nullptr, nullptr, nullptr);
    bias_softmax_kernel<<<dim3(NTOK, NHEAD), 256, 0, stream>>>(Sraw, pos_bins, pos_w, mask);
    pv_kernel<<<dim3(NTOK, NHEAD), 256, 0, stream>>>(Sraw, qkvg, attb);
    mfma_gemm<0><<<dim3(4, 8, 1), 256, 0, stream>>>(attb, wt_o, t1, nullptr,
        512, 512, 0, 0, 0, nullptr, nullptr, nullptr);
    mha_res_kernel<<<ND / 256, 256, 0, stream>>>(h, qkvg, t1, mask, h1);

    // ---- FFN ----
    ln_bf16_kernel<<<NTOK, 256, 0, stream>>>(h1, ln_ff_g, ln_ff_b, hnb);
    mfma_gemm<0><<<dim3(32, 8, 1), 256, 0, stream>>>(hnb, wt_13, ff13, nullptr,
        4096, 512, 0, 0, 0, nullptr, nullptr, nullptr);
    silu_mul_kernel<<<(1024 * 2048) / 256, 256, 0, stream>>>(ff13, ffb);
    mfma_gemm<0><<<dim3(4, 8, 1), 256, 0, stream>>>(ffb, wt_2, t1, nullptr,
        512, 2048, 0, 0, 0, nullptr, nullptr, nullptr);
    ffn_res_kernel<<<ND / 256, 256, 0, stream>>>(h1, t1, mask, out);   // h2 -> out[0:ND]

    // ---- Sinkhorn ----
    ln_bf16_kernel<<<NTOK, 256, 0, stream>>>(out, ln_sink_g, ln_sink_b, hnb);
    mfma_gemm<0><<<dim3(8, 8, 1), 256, 0, stream>>>(hnb, wt_qsks, qsks, nullptr,
        1024, 512, 0, 0, 0, nullptr, nullptr, nullptr);
    normvec_kernel<<<(NTOK * NHEAD) / 256, 256, 0, stream>>>(qsks);
    qkpad_kernel<<<4096, 256, 0, stream>>>(qsks, 1024, 0, 512, r_h, eps, Qp, Kp);
    mfma_gemm<1><<<dim3(8, 8, 16), 256, 0, stream>>>(Qp, Kp, nullptr, Sh,
        1024, 64, 65536, 65536, 1048576, alpha_h, eps, mask);
    mfma_gemm<1><<<dim3(8, 8, 16), 256, 0, stream>>>(Kp, Qp, nullptr, Sth,
        1024, 64, 65536, 65536, 1048576, alpha_h, eps, mask);

    hipMemsetAsync(gv, 0, NHEAD * NTOK * sizeof(float), stream);
    for (int it = 0; it < KIT; it++) {
        sink_pass_kernel<<<dim3(NTOK, NHEAD), 256, 0, stream>>>(Sh,  gv, mask, nv, fv);
        sink_pass_kernel<<<dim3(NTOK, NHEAD), 256, 0, stream>>>(Sth, fv, mask, nv, gv);
    }
    transport_kernel<<<dim3(NTOK, NHEAD), 256, 0, stream>>>(Sh, fv, gv, x_res, xc);

    final_kernel<<<NTOK, 256, 0, stream>>>(out, x_res, mask, ln_gate_g, ln_gate_b,
                                           w_gate_w, w_gate_b, lambda_raw, xc, out + ND);
}

// Round 3
// 805.094 us; speedup vs baseline: 4.6909x; 1.5796x over previous
//
#include <hip/hip_runtime.h>
#include <hip/hip_bf16.h>
#include <hip/hip_fp16.h>
#include <math.h>

#define NTOK 1024
#define DMODEL 512
#define NHEAD 16
#define DHEAD 32
#define DFF 2048
#define NBINS 68
#define KIT 20
#define NEGV (-1e9f)
#define NEGH (-30000.0f)   // masked logit sentinel for fp16 S storage

typedef __attribute__((ext_vector_type(8))) short bf16x8;
typedef __attribute__((ext_vector_type(4))) float f32x4;
typedef __attribute__((ext_vector_type(8))) unsigned short u16x8;

__device__ inline unsigned short f2bf(float f) {
    unsigned int u = __float_as_uint(f);
    unsigned int r = (u + 0x7fff + ((u >> 16) & 1)) >> 16;
    return (unsigned short)r;
}

// ---- block-wide reductions (256 threads = 4 waves), red4 = 4-float shared scratch ----
__device__ inline float block_max256(float v, float* red4) {
    #pragma unroll
    for (int s = 32; s; s >>= 1) v = fmaxf(v, __shfl_xor(v, s, 64));
    if ((threadIdx.x & 63) == 0) red4[threadIdx.x >> 6] = v;
    __syncthreads();
    v = fmaxf(fmaxf(red4[0], red4[1]), fmaxf(red4[2], red4[3]));
    __syncthreads();
    return v;
}
__device__ inline float block_sum256(float v, float* red4) {
    #pragma unroll
    for (int s = 32; s; s >>= 1) v += __shfl_xor(v, s, 64);
    if ((threadIdx.x & 63) == 0) red4[threadIdx.x >> 6] = v;
    __syncthreads();
    v = red4[0] + red4[1] + red4[2] + red4[3];
    __syncthreads();
    return v;
}

// ---------------- LayerNorm -> bf16 out ----------------
__global__ void ln_bf16_kernel(const float* __restrict__ x, const float* __restrict__ gm,
                               const float* __restrict__ bt, unsigned short* __restrict__ out) {
    int n = blockIdx.x;
    int tid = threadIdx.x;
    __shared__ float red[256];
    const float* row = x + (size_t)n * DMODEL;
    float a = row[tid], b = row[tid + 256];
    red[tid] = a + b;
    __syncthreads();
    for (int off = 128; off; off >>= 1) { if (tid < off) red[tid] += red[tid + off]; __syncthreads(); }
    float mu = red[0] * (1.0f / DMODEL);
    __syncthreads();
    float d0 = a - mu, d1 = b - mu;
    red[tid] = d0 * d0 + d1 * d1;
    __syncthreads();
    for (int off = 128; off; off >>= 1) { if (tid < off) red[tid] += red[tid + off]; __syncthreads(); }
    float rstd = rsqrtf(red[0] * (1.0f / DMODEL) + 1e-5f);
    out[(size_t)n * DMODEL + tid]       = f2bf(d0 * rstd * gm[tid] + bt[tid]);
    out[(size_t)n * DMODEL + tid + 256] = f2bf(d1 * rstd * gm[tid + 256] + bt[tid + 256]);
}

// ---------------- weight transpose + cast: Wt[n][k] = bf16(W[k][n]) ----------------
__global__ void wtrans_kernel(const float* __restrict__ W, unsigned short* __restrict__ Wt,
                              int K, int N) {
    __shared__ float T[32][33];
    int k0 = blockIdx.y * 32, n0 = blockIdx.x * 32, tid = threadIdx.x;
    int r = tid >> 3, c0 = (tid & 7) * 4;
    float4 v = *(const float4*)&W[(size_t)(k0 + r) * N + n0 + c0];
    T[r][c0] = v.x; T[r][c0 + 1] = v.y; T[r][c0 + 2] = v.z; T[r][c0 + 3] = v.w;
    __syncthreads();
    ushort4 o;
    o.x = f2bf(T[c0][r]); o.y = f2bf(T[c0 + 1][r]);
    o.z = f2bf(T[c0 + 2][r]); o.w = f2bf(T[c0 + 3][r]);
    *(ushort4*)&Wt[(size_t)(n0 + r) * K + k0 + c0] = o;
}

// ---------------- V transpose per head: Vt[h][d][m] = bf16(qkvg[m][1024 + h*32 + d]) ------
__global__ void vtrans_kernel(const float* __restrict__ qkvg, unsigned short* __restrict__ Vt) {
    __shared__ float T[32][33];
    int h = blockIdx.y, m0 = blockIdx.x * 32;
    int tid = threadIdx.x;
    int r = tid >> 3, c4 = (tid & 7) * 4;
    float4 v = *(const float4*)&qkvg[(size_t)(m0 + r) * 2048 + 1024 + h * 32 + c4];
    T[r][c4] = v.x; T[r][c4 + 1] = v.y; T[r][c4 + 2] = v.z; T[r][c4 + 3] = v.w;
    __syncthreads();
    ushort4 o;
    o.x = f2bf(T[c4][r]); o.y = f2bf(T[c4 + 1][r]);
    o.z = f2bf(T[c4 + 2][r]); o.w = f2bf(T[c4 + 3][r]);
    *(ushort4*)&Vt[(size_t)(h * 32 + r) * 1024 + m0 + c4] = o;
}

// ---------------- n_valid ----------------
__global__ void nvalid_kernel(const float* __restrict__ mask, float* __restrict__ nv) {
    __shared__ float red[256];
    int tid = threadIdx.x;
    red[tid] = mask[tid] + mask[tid + 256] + mask[tid + 512] + mask[tid + 768];
    __syncthreads();
    for (int off = 128; off; off >>= 1) { if (tid < off) red[tid] += red[tid + off]; __syncthreads(); }
    if (tid == 0) nv[0] = red[0];
}

// ---------------- MFMA GEMM: C[M][*] = A[M][K] @ Bt[*][K]^T (bf16 in, f32 acc) ----------
// 128x128 tile, BK=64, 256 thr = 4 waves (2x2), 4x4 16x16x32 frags/wave.
// MODE 0: store f32 C.  MODE 1: v += alpha[h]/eps[h]; mask row/col -> NEGH; store fp16.
// MODE 2: store bf16 Cb, only cols < N (B rows clamped to N-1 for staging).
template<int MODE>
__global__ __launch_bounds__(256)
void mfma_gemm(const unsigned short* __restrict__ A, const unsigned short* __restrict__ Bt,
               float* __restrict__ C, __half* __restrict__ Ch, unsigned short* __restrict__ Cb,
               int N, int K, int lda, int ldb, int ldc,
               long sA, long sB, long sC,
               const float* __restrict__ alpha, const float* __restrict__ epsv,
               const float* __restrict__ mask) {
    __shared__ unsigned short As[128 * 64];
    __shared__ unsigned short Bs[128 * 64];
    const int h = blockIdx.z;
    A += (size_t)h * sA; Bt += (size_t)h * sB;
    const int tid = threadIdx.x;
    const int lane = tid & 63, wid = tid >> 6;
    const int wr = wid >> 1, wc = wid & 1;
    const int lr = lane & 15, kg = lane >> 4;
    const int row0 = blockIdx.y * 128, col0 = blockIdx.x * 128;
    f32x4 acc[4][4];
    #pragma unroll
    for (int i = 0; i < 4; i++)
        #pragma unroll
        for (int j = 0; j < 4; j++) acc[i][j] = (f32x4){0.f, 0.f, 0.f, 0.f};

    for (int k0 = 0; k0 < K; k0 += 64) {
        #pragma unroll
        for (int i = 0; i < 4; i++) {           // stage 128x64 A and Bt tiles (swizzled)
            int cid = tid + i * 256;
            int r = cid >> 3, sl = cid & 7;
            int rb = col0 + r; if (rb > N - 1) rb = N - 1;   // clamp (PV: only 32 B-rows)
            u16x8 va = *(const u16x8*)&A[(size_t)(row0 + r) * lda + k0 + sl * 8];
            u16x8 vb = *(const u16x8*)&Bt[(size_t)rb * ldb + k0 + sl * 8];
            *(u16x8*)&As[r * 64 + ((sl ^ (r & 7)) * 8)] = va;
            *(u16x8*)&Bs[r * 64 + ((sl ^ (r & 7)) * 8)] = vb;
        }
        __syncthreads();
        #pragma unroll
        for (int ks = 0; ks < 2; ks++) {
            bf16x8 af[4], bfr[4];
            #pragma unroll
            for (int f = 0; f < 4; f++) {
                int ra = wr * 64 + f * 16 + lr;
                af[f] = *(const bf16x8*)&As[ra * 64 + (((ks * 4 + kg) ^ (ra & 7)) * 8)];
                int rb = wc * 64 + f * 16 + lr;
                bfr[f] = *(const bf16x8*)&Bs[rb * 64 + (((ks * 4 + kg) ^ (rb & 7)) * 8)];
            }
            #pragma unroll
            for (int i = 0; i < 4; i++)
                #pragma unroll
                for (int j = 0; j < 4; j++)
                    acc[i][j] = __builtin_amdgcn_mfma_f32_16x16x32_bf16(af[i], bfr[j], acc[i][j], 0, 0, 0);
        }
        __syncthreads();
    }
    float beta = 0.f;
    if (MODE == 1) beta = alpha[h] / epsv[h];
    #pragma unroll
    for (int i = 0; i < 4; i++) {
        int row = row0 + wr * 64 + i * 16 + kg * 4;
        #pragma unroll
        for (int j = 0; j < 4; j++) {
            int col = col0 + wc * 64 + j * 16 + lr;
            #pragma unroll
            for (int e = 0; e < 4; e++) {
                float v = acc[i][j][e];
                if (MODE == 0) {
                    C[(size_t)h * sC + (size_t)(row + e) * ldc + col] = v;
                } else if (MODE == 1) {
                    v += beta;
                    if (!(mask[row + e] > 0.f) || !(mask[col] > 0.f)) v = NEGH;
                    Ch[(size_t)h * sC + (size_t)(row + e) * ldc + col] = __float2half(v);
                } else {
                    if (col < N)
                        Cb[(size_t)h * sC + (size_t)(row + e) * ldc + col] = f2bf(v);
                }
            }
        }
    }
}

// ---------------- pad-cast Q,K per head into [H][N][64] bf16 (zero-padded K-dim) --------
__global__ void qkpad_kernel(const float* __restrict__ src, int stride, int qoff, int koff,
                             const float* __restrict__ rh, const float* __restrict__ ev,
                             unsigned short* __restrict__ Qp, unsigned short* __restrict__ Kp) {
    int idx = blockIdx.x * 256 + threadIdx.x;     // over 16*1024*64
    int k = idx & 63, n = (idx >> 6) & 1023, h = idx >> 16;
    float s = rh ? rh[h] / ev[h] : 0.17677669529663687f;
    unsigned short qv = 0, kv = 0;
    if (k < 32) {
        qv = f2bf(src[(size_t)n * stride + qoff + h * 32 + k] * s);
        kv = f2bf(src[(size_t)n * stride + koff + h * 32 + k]);
    }
    Qp[idx] = qv; Kp[idx] = kv;
}

// ---------------- attention: bias + mask + softmax; writes bf16 P in-place over row head --
__global__ void bias_softmax_kernel(float* __restrict__ S, const int* __restrict__ pos_bins,
                                    const float* __restrict__ pos_w, const float* __restrict__ mask) {
    int n = blockIdx.x, h = blockIdx.y, tid = threadIdx.x;
    __shared__ float red4[4];
    float* row = S + ((size_t)h * NTOK + n) * NTOK;
    float4 s4 = ((const float4*)row)[tid];
    int4 b4 = ((const int4*)(pos_bins + (size_t)n * NTOK))[tid];
    float4 m4 = ((const float4*)mask)[tid];
    float v0 = (m4.x > 0.f) ? s4.x + pos_w[b4.x * NHEAD + h] : NEGV;
    float v1 = (m4.y > 0.f) ? s4.y + pos_w[b4.y * NHEAD + h] : NEGV;
    float v2 = (m4.z > 0.f) ? s4.z + pos_w[b4.z * NHEAD + h] : NEGV;
    float v3 = (m4.w > 0.f) ? s4.w + pos_w[b4.w * NHEAD + h] : NEGV;
    float mx = block_max256(fmaxf(fmaxf(v0, v1), fmaxf(v2, v3)), red4);
    float p0 = __expf(v0 - mx), p1 = __expf(v1 - mx), p2 = __expf(v2 - mx), p3 = __expf(v3 - mx);
    float inv = 1.f / block_sum256(p0 + p1 + p2 + p3, red4);
    // all reads of this row happened before the barriers inside the reductions
    ushort4 o;
    o.x = f2bf(p0 * inv); o.y = f2bf(p1 * inv); o.z = f2bf(p2 * inv); o.w = f2bf(p3 * inv);
    *(ushort4*)&((unsigned short*)row)[tid * 4] = o;
}

// ---------------- h1 = h + sigmoid(G)*t1*mask ; G at qkvg cols [1536,2048) ----------------
__global__ void mha_res_kernel(const float* __restrict__ h, const float* __restrict__ qkvg,
                               const float* __restrict__ t1, const float* __restrict__ mask,
                               float* __restrict__ h1) {
    int i = blockIdx.x * 256 + threadIdx.x;
    int n = i >> 9, d = i & 511;
    float gval = qkvg[(size_t)n * 2048 + 1536 + d];
    float sg = 1.f / (1.f + __expf(-gval));
    h1[i] = h[i] + sg * t1[i] * mask[n];
}

// ---------------- silu(ff1)*ff3 from fused [1024][4096] -> bf16 [1024][2048] ----------------
__global__ void silu_mul_kernel(const float* __restrict__ ff, unsigned short* __restrict__ ffb) {
    int i = blockIdx.x * 256 + threadIdx.x;   // over 1024*2048
    int n = i >> 11, c = i & 2047;
    float x = ff[(size_t)n * 4096 + c], y = ff[(size_t)n * 4096 + 2048 + c];
    ffb[i] = f2bf(x / (1.f + __expf(-x)) * y);
}

// ---------------- out = h1 + t1*mask ----------------
__global__ void ffn_res_kernel(const float* __restrict__ h1, const float* __restrict__ t1,
                               const float* __restrict__ mask, float* __restrict__ out) {
    int i = blockIdx.x * 256 + threadIdx.x;
    out[i] = h1[i] + t1[i] * mask[i >> 9];
}

// ---------------- normalize per-head 32-vectors in fused qs|ks [1024][1024] ----------------
__global__ void normvec_kernel(float* __restrict__ qsks) {
    int idx = blockIdx.x * 256 + threadIdx.x;   // 16384
    int n = idx >> 4, h = idx & 15;
    float* p = &qsks[(size_t)n * 1024 + h * 32];
    float ss = 0.f;
    #pragma unroll
    for (int d = 0; d < 32; d++) ss += p[d] * p[d];
    float inv = 1.f / fmaxf(sqrtf(ss), 1e-12f);
    #pragma unroll
    for (int d = 0; d < 32; d++) p[d] *= inv;
    float* p2 = &qsks[(size_t)n * 1024 + 512 + h * 32];
    ss = 0.f;
    #pragma unroll
    for (int d = 0; d < 32; d++) ss += p2[d] * p2[d];
    inv = 1.f / fmaxf(sqrtf(ss), 1e-12f);
    #pragma unroll
    for (int d = 0; d < 32; d++) p2[d] *= inv;
}

// ---------------- sinkhorn pass, wave-per-row: out[row] = la - LSE_j(S[row,j] + dual[j]) --
__global__ void sink_pass_kernel(const __half* __restrict__ Sb, const float* __restrict__ dual,
                                 const float* __restrict__ mask, const float* __restrict__ nv,
                                 float* __restrict__ outv) {
    int wid = threadIdx.x >> 6, lane = threadIdx.x & 63;
    int row = blockIdx.x * 4 + wid;          // row = h*1024 + i
    int h = row >> 10, i = row & 1023;
    const __half2* r2 = (const __half2*)(Sb + (size_t)row * NTOK) + lane * 8;
    const float4* d4 = (const float4*)(dual + (size_t)h * NTOK) + lane * 4;
    float v[16], dv[16];
    *(float4*)&dv[0]  = d4[0]; *(float4*)&dv[4]  = d4[1];
    *(float4*)&dv[8]  = d4[2]; *(float4*)&dv[12] = d4[3];
    #pragma unroll
    for (int j = 0; j < 8; j++) {
        float2 f = __half22float2(r2[j]);
        v[2 * j] = f.x; v[2 * j + 1] = f.y;
    }
    float mx = -INFINITY;
    #pragma unroll
    for (int j = 0; j < 16; j++) { v[j] += dv[j]; mx = fmaxf(mx, v[j]); }
    #pragma unroll
    for (int s = 32; s; s >>= 1) mx = fmaxf(mx, __shfl_xor(mx, s, 64));
    float sum = 0.f;
    #pragma unroll
    for (int j = 0; j < 16; j++) sum += __expf(v[j] - mx);
    #pragma unroll
    for (int s = 32; s; s >>= 1) sum += __shfl_xor(sum, s, 64);
    if (lane == 0) {
        float la = (mask[i] > 0.f) ? -__logf(nv[0]) : NEGV;
        outv[row] = la - (mx + __logf(sum));
    }
}

// ---------------- transport: xc[h,n,:] = softmax_m(f + S + g) @ x_res ----------------
__global__ void transport_kernel(const __half* __restrict__ Sb, const float* __restrict__ f,
                                 const float* __restrict__ g, const float* __restrict__ x_res,
                                 float* __restrict__ xc) {
    int n = blockIdx.x, h = blockIdx.y, tid = threadIdx.x;
    __shared__ float red4[4];
    const __half2* r2 = (const __half2*)(Sb + ((size_t)h * NTOK + n) * NTOK);
    __half2 p0 = r2[tid * 2], p1 = r2[tid * 2 + 1];
    float2 fa = __half22float2(p0), fb = __half22float2(p1);
    float4 d4 = ((const float4*)(g + (size_t)h * NTOK))[tid];
    float fr = f[(size_t)h * NTOK + n];
    float v0 = fr + fa.x + d4.x, v1 = fr + fa.y + d4.y;
    float v2 = fr + fb.x + d4.z, v3 = fr + fb.y + d4.w;
    float mx = block_max256(fmaxf(fmaxf(v0, v1), fmaxf(v2, v3)), red4);
    float e0 = __expf(v0 - mx), e1 = __expf(v1 - mx), e2 = __expf(v2 - mx), e3 = __expf(v3 - mx);
    int m = tid * 4;
    float sum = block_sum256(e0 + e1 + e2 + e3, red4);
    float a0 = block_sum256(e0 * x_res[m * 3] + e1 * x_res[m * 3 + 3] + e2 * x_res[m * 3 + 6] + e3 * x_res[m * 3 + 9], red4);
    float a1 = block_sum256(e0 * x_res[m * 3 + 1] + e1 * x_res[m * 3 + 4] + e2 * x_res[m * 3 + 7] + e3 * x_res[m * 3 + 10], red4);
    float a2 = block_sum256(e0 * x_res[m * 3 + 2] + e1 * x_res[m * 3 + 5] + e2 * x_res[m * 3 + 8] + e3 * x_res[m * 3 + 11], red4);
    if (tid == 0) {
        float inv = 1.f / sum;
        xc[((size_t)h * NTOK + n) * 3 + 0] = a0 * inv;
        xc[((size_t)h * NTOK + n) * 3 + 1] = a1 * inv;
        xc[((size_t)h * NTOK + n) * 3 + 2] = a2 * inv;
    }
}

// ---------------- final: gate = sigmoid(LN(h2)@wg + b); x_out = x_res + gate*disp*mask ----
__global__ void final_kernel(const float* __restrict__ h2, const float* __restrict__ x_res,
                             const float* __restrict__ mask, const float* __restrict__ gm,
                             const float* __restrict__ bt, const float* __restrict__ wg,
                             const float* __restrict__ wb, const float* __restrict__ lamraw,
                             const float* __restrict__ xc, float* __restrict__ xout) {
    int n = blockIdx.x;
    int tid = threadIdx.x;
    __shared__ float red[256];
    const float* row = h2 + (size_t)n * DMODEL;
    float a = row[tid], b = row[tid + 256];
    red[tid] = a + b;
    __syncthreads();
    for (int off = 128; off; off >>= 1) { if (tid < off) red[tid] += red[tid + off]; __syncthreads(); }
    float mu = red[0] * (1.0f / DMODEL);
    __syncthreads();
    float d0 = a - mu, d1 = b - mu;
    red[tid] = d0 * d0 + d1 * d1;
    __syncthreads();
    for (int off = 128; off; off >>= 1) { if (tid < off) red[tid] += red[tid + off]; __syncthreads(); }
    float rstd = rsqrtf(red[0] * (1.0f / DMODEL) + 1e-5f);
    __syncthreads();
    float t0 = (d0 * rstd * gm[tid] + bt[tid]) * wg[tid];
    float t1 = (d1 * rstd * gm[tid + 256] + bt[tid + 256]) * wg[tid + 256];
    red[tid] = t0 + t1;
    __syncthreads();
    for (int off = 128; off; off >>= 1) { if (tid < off) red[tid] += red[tid + off]; __syncthreads(); }
    if (tid == 0) {
        float gate = 1.f / (1.f + expf(-(red[0] + wb[0])));
        float mk = mask[n];
        #pragma unroll
        for (int c = 0; c < 3; c++) {
            float xr = x_res[n * 3 + c];
            float disp = 0.f;
            for (int h = 0; h < NHEAD; h++) {
                float lam = tanhf(lamraw[h]) * (1.f / NHEAD);
                disp += lam * (xc[((size_t)h * NTOK + n) * 3 + c] - xr);
            }
            xout[n * 3 + c] = xr + gate * disp * mk;
        }
    }
}

extern "C" void kernel_launch(void* const* d_in, const int* in_sizes, int n_in,
                              void* d_out, int out_size, void* d_ws, size_t ws_size,
                              hipStream_t stream) {
    const float* h          = (const float*)d_in[0];
    const float* x_res      = (const float*)d_in[1];
    const int*   pos_bins   = (const int*)d_in[2];
    const float* mask       = (const float*)d_in[3];
    const float* ln_mha_g   = (const float*)d_in[4];
    const float* ln_mha_b   = (const float*)d_in[5];
    const float* w_q        = (const float*)d_in[6];
    const float* w_k        = (const float*)d_in[7];
    const float* w_v        = (const float*)d_in[8];
    const float* w_g        = (const float*)d_in[9];
    const float* w_o        = (const float*)d_in[10];
    const float* pos_w      = (const float*)d_in[11];
    const float* ln_ff_g    = (const float*)d_in[12];
    const float* ln_ff_b    = (const float*)d_in[13];
    const float* sw_w1      = (const float*)d_in[14];
    const float* sw_w3      = (const float*)d_in[15];
    const float* sw_w2      = (const float*)d_in[16];
    const float* ln_sink_g  = (const float*)d_in[17];
    const float* ln_sink_b  = (const float*)d_in[18];
    const float* w_q_sink   = (const float*)d_in[19];
    const float* w_k_sink   = (const float*)d_in[20];
    const float* alpha_h    = (const float*)d_in[21];
    const float* r_h        = (const float*)d_in[22];
    const float* eps        = (const float*)d_in[23];
    const float* ln_gate_g  = (const float*)d_in[24];
    const float* ln_gate_b  = (const float*)d_in[25];
    const float* w_gate_w   = (const float*)d_in[26];
    const float* w_gate_b   = (const float*)d_in[27];
    const float* lambda_raw = (const float*)d_in[28];
    float* out = (float*)d_out;
    const size_t ND = (size_t)NTOK * DMODEL;

    // ---- workspace bump allocator (256B aligned) ----
    char* Wp = (char*)d_ws;
    auto alloc = [&](size_t bytes) { char* p = Wp; Wp += (bytes + 255) & ~(size_t)255; return p; };
    unsigned short* wt_qkvg = (unsigned short*)alloc((size_t)2048 * 512 * 2);
    unsigned short* wt_o    = (unsigned short*)alloc((size_t)512 * 512 * 2);
    unsigned short* wt_13   = (unsigned short*)alloc((size_t)4096 * 512 * 2);
    unsigned short* wt_2    = (unsigned short*)alloc((size_t)512 * 2048 * 2);
    unsigned short* wt_qsks = (unsigned short*)alloc((size_t)1024 * 512 * 2);
    unsigned short* hnb     = (unsigned short*)alloc(ND * 2);
    float*          qkvg    = (float*)alloc((size_t)1024 * 2048 * 4);     // also reused as qs|ks f32
    unsigned short* attb    = (unsigned short*)alloc(ND * 2);
    float*          t1      = (float*)alloc(ND * 4);
    float*          h1      = (float*)alloc(ND * 4);
    unsigned short* ffb     = (unsigned short*)alloc((size_t)1024 * 2048 * 2);
    unsigned short* Qp      = (unsigned short*)alloc((size_t)16 * 1024 * 64 * 2);
    unsigned short* Kp      = (unsigned short*)alloc((size_t)16 * 1024 * 64 * 2);
    unsigned short* Vt      = (unsigned short*)alloc((size_t)16 * 32 * 1024 * 2);
    char*           R       = alloc((size_t)64 * 1024 * 1024);            // big shared region
    float*          fv      = (float*)alloc((size_t)16 * 1024 * 4);
    float*          gv      = (float*)alloc((size_t)16 * 1024 * 4);
    float*          xc      = (float*)alloc((size_t)16 * 1024 * 3 * 4);
    float*          nv      = (float*)alloc(256);

    float*  Sraw  = (float*)R;                                  // attention scores -> bf16 P rows
    float*  ff13  = (float*)R;                                  // FFN fused out (16MB)
    __half* Sh    = (__half*)R;                                 // sinkhorn S fp16 (32MB)
    __half* Sth   = (__half*)(R + (size_t)32 * 1024 * 1024);    // sinkhorn S^T fp16 (32MB)
    float*  qsks  = qkvg;

    nvalid_kernel<<<1, 256, 0, stream>>>(mask, nv);

    // ---- weight prep (order-independent) ----
    wtrans_kernel<<<dim3(512/32, 512/32), 256, 0, stream>>>(w_q, wt_qkvg,                512, 512);
    wtrans_kernel<<<dim3(512/32, 512/32), 256, 0, stream>>>(w_k, wt_qkvg + 512*512,      512, 512);
    wtrans_kernel<<<dim3(512/32, 512/32), 256, 0, stream>>>(w_v, wt_qkvg + 2*512*512,    512, 512);
    wtrans_kernel<<<dim3(512/32, 512/32), 256, 0, stream>>>(w_g, wt_qkvg + 3*512*512,    512, 512);
    wtrans_kernel<<<dim3(512/32, 512/32), 256, 0, stream>>>(w_o, wt_o,                   512, 512);
    wtrans_kernel<<<dim3(2048/32, 512/32), 256, 0, stream>>>(sw_w1, wt_13,               512, 2048);
    wtrans_kernel<<<dim3(2048/32, 512/32), 256, 0, stream>>>(sw_w3, wt_13 + 2048*512,    512, 2048);
    wtrans_kernel<<<dim3(512/32, 2048/32), 256, 0, stream>>>(sw_w2, wt_2,                2048, 512);
    wtrans_kernel<<<dim3(512/32, 512/32), 256, 0, stream>>>(w_q_sink, wt_qsks,           512, 512);
    wtrans_kernel<<<dim3(512/32, 512/32), 256, 0, stream>>>(w_k_sink, wt_qsks + 512*512, 512, 512);

    // ---- MHA ----
    ln_bf16_kernel<<<NTOK, 256, 0, stream>>>(h, ln_mha_g, ln_mha_b, hnb);
    mfma_gemm<0><<<dim3(16, 8, 1), 256, 0, stream>>>(hnb, wt_qkvg, qkvg, nullptr, nullptr,
        2048, 512, 512, 512, 2048, 0, 0, 0, nullptr, nullptr, nullptr);
    qkpad_kernel<<<4096, 256, 0, stream>>>(qkvg, 2048, 0, 512, nullptr, nullptr, Qp, Kp);
    vtrans_kernel<<<dim3(32, 16), 256, 0, stream>>>(qkvg, Vt);
    mfma_gemm<0><<<dim3(8, 8, 16), 256, 0, stream>>>(Qp, Kp, Sraw, nullptr, nullptr,
        1024, 64, 64, 64, 1024, 65536, 65536, 1048576, nullptr, nullptr, nullptr);
    bias_softmax_kernel<<<dim3(NTOK, NHEAD), 256, 0, stream>>>(Sraw, pos_bins, pos_w, mask);
    // PV: A = bf16 P rows (stride 2048 elems inside f32 S rows), Bt = Vt[h] (32 rows)
    mfma_gemm<2><<<dim3(1, 8, 16), 256, 0, stream>>>((const unsigned short*)Sraw, Vt,
        nullptr, nullptr, attb,
        32, 1024, 2048, 1024, 512, 2097152, 32768, 32, nullptr, nullptr, nullptr);
    mfma_gemm<0><<<dim3(4, 8, 1), 256, 0, stream>>>(attb, wt_o, t1, nullptr, nullptr,
        512, 512, 512, 512, 512, 0, 0, 0, nullptr, nullptr, nullptr);
    mha_res_kernel<<<ND / 256, 256, 0, stream>>>(h, qkvg, t1, mask, h1);

    // ---- FFN ----
    ln_bf16_kernel<<<NTOK, 256, 0, stream>>>(h1, ln_ff_g, ln_ff_b, hnb);
    mfma_gemm<0><<<dim3(32, 8, 1), 256, 0, stream>>>(hnb, wt_13, ff13, nullptr, nullptr,
        4096, 512, 512, 512, 4096, 0, 0, 0, nullptr, nullptr, nullptr);
    silu_mul_kernel<<<(1024 * 2048) / 256, 256, 0, stream>>>(ff13, ffb);
    mfma_gemm<0><<<dim3(4, 8, 1), 256, 0, stream>>>(ffb, wt_2, t1, nullptr, nullptr,
        512, 2048, 2048, 2048, 512, 0, 0, 0, nullptr, nullptr, nullptr);
    ffn_res_kernel<<<ND / 256, 256, 0, stream>>>(h1, t1, mask, out);   // h2 -> out[0:ND]

    // ---- Sinkhorn ----
    ln_bf16_kernel<<<NTOK, 256, 0, stream>>>(out, ln_sink_g, ln_sink_b, hnb);
    mfma_gemm<0><<<dim3(8, 8, 1), 256, 0, stream>>>(hnb, wt_qsks, qsks, nullptr, nullptr,
        1024, 512, 512, 512, 1024, 0, 0, 0, nullptr, nullptr, nullptr);
    normvec_kernel<<<(NTOK * NHEAD) / 256, 256, 0, stream>>>(qsks);
    qkpad_kernel<<<4096, 256, 0, stream>>>(qsks, 1024, 0, 512, r_h, eps, Qp, Kp);
    mfma_gemm<1><<<dim3(8, 8, 16), 256, 0, stream>>>(Qp, Kp, nullptr, Sh, nullptr,
        1024, 64, 64, 64, 1024, 65536, 65536, 1048576, alpha_h, eps, mask);
    mfma_gemm<1><<<dim3(8, 8, 16), 256, 0, stream>>>(Kp, Qp, nullptr, Sth, nullptr,
        1024, 64, 64, 64, 1024, 65536, 65536, 1048576, alpha_h, eps, mask);

    hipMemsetAsync(gv, 0, NHEAD * NTOK * sizeof(float), stream);
    for (int it = 0; it < KIT; it++) {
        sink_pass_kernel<<<4096, 256, 0, stream>>>(Sh,  gv, mask, nv, fv);
        sink_pass_kernel<<<4096, 256, 0, stream>>>(Sth, fv, mask, nv, gv);
    }
    transport_kernel<<<dim3(NTOK, NHEAD), 256, 0, stream>>>(Sh, fv, gv, x_res, xc);

    final_kernel<<<NTOK, 256, 0, stream>>>(out, x_res, mask, ln_gate_g, ln_gate_b,
                                           w_gate_w, w_gate_b, lambda_raw, xc, out + ND);
}

// Round 4
// 753.848 us; speedup vs baseline: 5.0098x; 1.0680x over previous
//
#include <hip/hip_runtime.h>
#include <hip/hip_bf16.h>
#include <hip/hip_fp16.h>
#include <math.h>

#define NTOK 1024
#define DMODEL 512
#define NHEAD 16
#define DHEAD 32
#define DFF 2048
#define NBINS 68
#define KIT 20
#define NEGV (-1e9f)
#define NEGH (-30000.0f)   // masked logit sentinel for fp16 S storage

typedef __attribute__((ext_vector_type(8))) short bf16x8;
typedef __attribute__((ext_vector_type(4))) float f32x4;
typedef __attribute__((ext_vector_type(8))) unsigned short u16x8;

__device__ inline unsigned short f2bf(float f) {
    unsigned int u = __float_as_uint(f);
    unsigned int r = (u + 0x7fff + ((u >> 16) & 1)) >> 16;
    return (unsigned short)r;
}

__device__ inline float wave_max64(float v) {
    #pragma unroll
    for (int s = 32; s; s >>= 1) v = fmaxf(v, __shfl_xor(v, s, 64));
    return v;
}
__device__ inline float wave_sum64(float v) {
    #pragma unroll
    for (int s = 32; s; s >>= 1) v += __shfl_xor(v, s, 64);
    return v;
}

// ---------------- LayerNorm -> bf16 out ----------------
__global__ void ln_bf16_kernel(const float* __restrict__ x, const float* __restrict__ gm,
                               const float* __restrict__ bt, unsigned short* __restrict__ out) {
    int n = blockIdx.x;
    int tid = threadIdx.x;
    __shared__ float red[256];
    const float* row = x + (size_t)n * DMODEL;
    float a = row[tid], b = row[tid + 256];
    red[tid] = a + b;
    __syncthreads();
    for (int off = 128; off; off >>= 1) { if (tid < off) red[tid] += red[tid + off]; __syncthreads(); }
    float mu = red[0] * (1.0f / DMODEL);
    __syncthreads();
    float d0 = a - mu, d1 = b - mu;
    red[tid] = d0 * d0 + d1 * d1;
    __syncthreads();
    for (int off = 128; off; off >>= 1) { if (tid < off) red[tid] += red[tid + off]; __syncthreads(); }
    float rstd = rsqrtf(red[0] * (1.0f / DMODEL) + 1e-5f);
    out[(size_t)n * DMODEL + tid]       = f2bf(d0 * rstd * gm[tid] + bt[tid]);
    out[(size_t)n * DMODEL + tid + 256] = f2bf(d1 * rstd * gm[tid + 256] + bt[tid + 256]);
}

// ---------------- weight transpose + cast: Wt[n][k] = bf16(W[k][n]) ----------------
__global__ void wtrans_kernel(const float* __restrict__ W, unsigned short* __restrict__ Wt,
                              int K, int N) {
    __shared__ float T[32][33];
    int k0 = blockIdx.y * 32, n0 = blockIdx.x * 32, tid = threadIdx.x;
    int r = tid >> 3, c0 = (tid & 7) * 4;
    float4 v = *(const float4*)&W[(size_t)(k0 + r) * N + n0 + c0];
    T[r][c0] = v.x; T[r][c0 + 1] = v.y; T[r][c0 + 2] = v.z; T[r][c0 + 3] = v.w;
    __syncthreads();
    ushort4 o;
    o.x = f2bf(T[c0][r]); o.y = f2bf(T[c0 + 1][r]);
    o.z = f2bf(T[c0 + 2][r]); o.w = f2bf(T[c0 + 3][r]);
    *(ushort4*)&Wt[(size_t)(n0 + r) * K + k0 + c0] = o;
}

// ---------------- V transpose per head: Vt[h][d][m] = bf16(qkvg[m][1024 + h*32 + d]) ------
__global__ void vtrans_kernel(const float* __restrict__ qkvg, unsigned short* __restrict__ Vt) {
    __shared__ float T[32][33];
    int h = blockIdx.y, m0 = blockIdx.x * 32;
    int tid = threadIdx.x;
    int r = tid >> 3, c4 = (tid & 7) * 4;
    float4 v = *(const float4*)&qkvg[(size_t)(m0 + r) * 2048 + 1024 + h * 32 + c4];
    T[r][c4] = v.x; T[r][c4 + 1] = v.y; T[r][c4 + 2] = v.z; T[r][c4 + 3] = v.w;
    __syncthreads();
    ushort4 o;
    o.x = f2bf(T[c4][r]); o.y = f2bf(T[c4 + 1][r]);
    o.z = f2bf(T[c4 + 2][r]); o.w = f2bf(T[c4 + 3][r]);
    *(ushort4*)&Vt[(size_t)(h * 32 + r) * 1024 + m0 + c4] = o;
}

// ---------------- n_valid ----------------
__global__ void nvalid_kernel(const float* __restrict__ mask, float* __restrict__ nv) {
    __shared__ float red[256];
    int tid = threadIdx.x;
    red[tid] = mask[tid] + mask[tid + 256] + mask[tid + 512] + mask[tid + 768];
    __syncthreads();
    for (int off = 128; off; off >>= 1) { if (tid < off) red[tid] += red[tid + off]; __syncthreads(); }
    if (tid == 0) nv[0] = red[0];
}

// ---------------- MFMA GEMM: C[M][*] = A[M][K] @ Bt[*][K]^T (bf16 in, f32 acc) ----------
// 128x128 tile, BK=64, 256 thr = 4 waves (2x2), 4x4 16x16x32 frags/wave.
// MODE 0: store f32 C.  MODE 1: v += alpha[h]/eps[h]; mask row/col -> NEGH; store fp16.
// MODE 2: store bf16 Cb, only cols < N (B rows clamped for staging).
// MODE 3: store fp16 Ch plain.
template<int MODE>
__global__ __launch_bounds__(256)
void mfma_gemm(const unsigned short* __restrict__ A, const unsigned short* __restrict__ Bt,
               float* __restrict__ C, __half* __restrict__ Ch, unsigned short* __restrict__ Cb,
               int N, int K, int lda, int ldb, int ldc,
               long sA, long sB, long sC,
               const float* __restrict__ alpha, const float* __restrict__ epsv,
               const float* __restrict__ mask) {
    __shared__ unsigned short As[128 * 64];
    __shared__ unsigned short Bs[128 * 64];
    const int h = blockIdx.z;
    A += (size_t)h * sA; Bt += (size_t)h * sB;
    const int tid = threadIdx.x;
    const int lane = tid & 63, wid = tid >> 6;
    const int wr = wid >> 1, wc = wid & 1;
    const int lr = lane & 15, kg = lane >> 4;
    const int row0 = blockIdx.y * 128, col0 = blockIdx.x * 128;
    f32x4 acc[4][4];
    #pragma unroll
    for (int i = 0; i < 4; i++)
        #pragma unroll
        for (int j = 0; j < 4; j++) acc[i][j] = (f32x4){0.f, 0.f, 0.f, 0.f};

    for (int k0 = 0; k0 < K; k0 += 64) {
        #pragma unroll
        for (int i = 0; i < 4; i++) {           // stage 128x64 A and Bt tiles (swizzled)
            int cid = tid + i * 256;
            int r = cid >> 3, sl = cid & 7;
            int rb = col0 + r; if (rb > N - 1) rb = N - 1;   // clamp (PV: only 32 B-rows)
            u16x8 va = *(const u16x8*)&A[(size_t)(row0 + r) * lda + k0 + sl * 8];
            u16x8 vb = *(const u16x8*)&Bt[(size_t)rb * ldb + k0 + sl * 8];
            *(u16x8*)&As[r * 64 + ((sl ^ (r & 7)) * 8)] = va;
            *(u16x8*)&Bs[r * 64 + ((sl ^ (r & 7)) * 8)] = vb;
        }
        __syncthreads();
        #pragma unroll
        for (int ks = 0; ks < 2; ks++) {
            bf16x8 af[4], bfr[4];
            #pragma unroll
            for (int f = 0; f < 4; f++) {
                int ra = wr * 64 + f * 16 + lr;
                af[f] = *(const bf16x8*)&As[ra * 64 + (((ks * 4 + kg) ^ (ra & 7)) * 8)];
                int rb = wc * 64 + f * 16 + lr;
                bfr[f] = *(const bf16x8*)&Bs[rb * 64 + (((ks * 4 + kg) ^ (rb & 7)) * 8)];
            }
            #pragma unroll
            for (int i = 0; i < 4; i++)
                #pragma unroll
                for (int j = 0; j < 4; j++)
                    acc[i][j] = __builtin_amdgcn_mfma_f32_16x16x32_bf16(af[i], bfr[j], acc[i][j], 0, 0, 0);
        }
        __syncthreads();
    }
    float beta = 0.f;
    if (MODE == 1) beta = alpha[h] / epsv[h];
    #pragma unroll
    for (int i = 0; i < 4; i++) {
        int row = row0 + wr * 64 + i * 16 + kg * 4;
        #pragma unroll
        for (int j = 0; j < 4; j++) {
            int col = col0 + wc * 64 + j * 16 + lr;
            #pragma unroll
            for (int e = 0; e < 4; e++) {
                float v = acc[i][j][e];
                if (MODE == 0) {
                    C[(size_t)h * sC + (size_t)(row + e) * ldc + col] = v;
                } else if (MODE == 1) {
                    v += beta;
                    if (!(mask[row + e] > 0.f) || !(mask[col] > 0.f)) v = NEGH;
                    Ch[(size_t)h * sC + (size_t)(row + e) * ldc + col] = __float2half(v);
                } else if (MODE == 2) {
                    if (col < N)
                        Cb[(size_t)h * sC + (size_t)(row + e) * ldc + col] = f2bf(v);
                } else {
                    Ch[(size_t)h * sC + (size_t)(row + e) * ldc + col] = __float2half(v);
                }
            }
        }
    }
}

// ---------------- pad-cast Q,K per head into [H][N][64] bf16 (zero-padded K-dim) --------
__global__ void qkpad_kernel(const float* __restrict__ src, int stride, int qoff, int koff,
                             const float* __restrict__ rh, const float* __restrict__ ev,
                             unsigned short* __restrict__ Qp, unsigned short* __restrict__ Kp) {
    int idx = blockIdx.x * 256 + threadIdx.x;     // over 16*1024*64
    int k = idx & 63, n = (idx >> 6) & 1023, h = idx >> 16;
    float s = rh ? rh[h] / ev[h] : 0.17677669529663687f;
    unsigned short qv = 0, kv = 0;
    if (k < 32) {
        qv = f2bf(src[(size_t)n * stride + qoff + h * 32 + k] * s);
        kv = f2bf(src[(size_t)n * stride + koff + h * 32 + k]);
    }
    Qp[idx] = qv; Kp[idx] = kv;
}

// ---------------- attention: bias + mask + softmax over fp16 S; writes bf16 P in place ----
// one block per n; 4 waves x 4 heads; bins+pos_w staged in LDS once.
__global__ __launch_bounds__(256)
void bias_softmax_kernel(__half* __restrict__ S, const int* __restrict__ pos_bins,
                         const float* __restrict__ pos_w, const float* __restrict__ mask) {
    __shared__ int   bins_s[NTOK];
    __shared__ float pw_s[NBINS * NHEAD];
    int n = blockIdx.x, tid = threadIdx.x;
    int lane = tid & 63, wid = tid >> 6;
    #pragma unroll
    for (int i = 0; i < 4; i++) {
        int m = tid + i * 256;
        int b = pos_bins[(size_t)n * NTOK + m];
        bins_s[m] = (mask[m] > 0.f) ? b : -1;
    }
    #pragma unroll
    for (int i = 0; i < 5; i++) {
        int idx = tid + i * 256;
        if (idx < NBINS * NHEAD) pw_s[idx] = pos_w[idx];
    }
    __syncthreads();
    int mb = lane * 16;
    #pragma unroll
    for (int hh = 0; hh < 4; hh++) {
        int h = wid * 4 + hh;
        __half* row = S + ((size_t)h * NTOK + n) * NTOK;
        uint4 ua = ((const uint4*)row)[lane * 2];
        uint4 ub = ((const uint4*)row)[lane * 2 + 1];
        unsigned uu[8] = {ua.x, ua.y, ua.z, ua.w, ub.x, ub.y, ub.z, ub.w};
        float v[16];
        #pragma unroll
        for (int j = 0; j < 8; j++) {
            float2 f = __half22float2(*(__half2*)&uu[j]);
            v[2 * j] = f.x; v[2 * j + 1] = f.y;
        }
        float mx = -INFINITY;
        #pragma unroll
        for (int j = 0; j < 16; j++) {
            int b = bins_s[mb + j];
            v[j] = (b >= 0) ? v[j] + pw_s[b * NHEAD + h] : NEGV;
            mx = fmaxf(mx, v[j]);
        }
        mx = wave_max64(mx);
        float sum = 0.f;
        #pragma unroll
        for (int j = 0; j < 16; j++) { v[j] = __expf(v[j] - mx); sum += v[j]; }
        float inv = 1.f / wave_sum64(sum);
        unsigned short o[16];
        #pragma unroll
        for (int j = 0; j < 16; j++) o[j] = f2bf(v[j] * inv);
        ((uint4*)row)[lane * 2]     = *(uint4*)&o[0];
        ((uint4*)row)[lane * 2 + 1] = *(uint4*)&o[8];
    }
}

// ---------------- h1 = h + sigmoid(G)*t1*mask ; G at qkvg cols [1536,2048) ----------------
__global__ void mha_res_kernel(const float* __restrict__ h, const float* __restrict__ qkvg,
                               const float* __restrict__ t1, const float* __restrict__ mask,
                               float* __restrict__ h1) {
    int i = blockIdx.x * 256 + threadIdx.x;
    int n = i >> 9, d = i & 511;
    float gval = qkvg[(size_t)n * 2048 + 1536 + d];
    float sg = 1.f / (1.f + __expf(-gval));
    h1[i] = h[i] + sg * t1[i] * mask[n];
}

// ---------------- silu(ff1)*ff3 from fused [1024][4096] -> bf16 [1024][2048] ----------------
__global__ void silu_mul_kernel(const float* __restrict__ ff, unsigned short* __restrict__ ffb) {
    int i = blockIdx.x * 256 + threadIdx.x;   // over 1024*2048
    int n = i >> 11, c = i & 2047;
    float x = ff[(size_t)n * 4096 + c], y = ff[(size_t)n * 4096 + 2048 + c];
    ffb[i] = f2bf(x / (1.f + __expf(-x)) * y);
}

// ---------------- out = h1 + t1*mask ----------------
__global__ void ffn_res_kernel(const float* __restrict__ h1, const float* __restrict__ t1,
                               const float* __restrict__ mask, float* __restrict__ out) {
    int i = blockIdx.x * 256 + threadIdx.x;
    out[i] = h1[i] + t1[i] * mask[i >> 9];
}

// ---------------- normalize per-head 32-vectors in fused qs|ks [1024][1024] ----------------
__global__ void normvec_kernel(float* __restrict__ qsks) {
    int idx = blockIdx.x * 256 + threadIdx.x;   // 16384
    int n = idx >> 4, h = idx & 15;
    float* p = &qsks[(size_t)n * 1024 + h * 32];
    float ss = 0.f;
    #pragma unroll
    for (int d = 0; d < 32; d++) ss += p[d] * p[d];
    float inv = 1.f / fmaxf(sqrtf(ss), 1e-12f);
    #pragma unroll
    for (int d = 0; d < 32; d++) p[d] *= inv;
    float* p2 = &qsks[(size_t)n * 1024 + 512 + h * 32];
    ss = 0.f;
    #pragma unroll
    for (int d = 0; d < 32; d++) ss += p2[d] * p2[d];
    inv = 1.f / fmaxf(sqrtf(ss), 1e-12f);
    #pragma unroll
    for (int d = 0; d < 32; d++) p2[d] *= inv;
}

// ---------------- sinkhorn pass: 8 rows/block, 2 rows/wave, shuffle-only reductions ------
__global__ __launch_bounds__(256)
void sink_pass_kernel(const __half* __restrict__ Sb, const float* __restrict__ dual,
                      const float* __restrict__ mask, const float* __restrict__ nv,
                      float* __restrict__ outv) {
    int tid = threadIdx.x, lane = tid & 63, wid = tid >> 6;
    int row0 = blockIdx.x * 8;
    int h = row0 >> 10;
    const float4* dp = (const float4*)(dual + ((size_t)h << 10));
    float4 d0 = dp[lane * 4], d1 = dp[lane * 4 + 1], d2 = dp[lane * 4 + 2], d3 = dp[lane * 4 + 3];
    float dv[16];
    *(float4*)&dv[0] = d0; *(float4*)&dv[4] = d1; *(float4*)&dv[8] = d2; *(float4*)&dv[12] = d3;
    #pragma unroll
    for (int r = 0; r < 2; r++) {
        int row = row0 + wid * 2 + r;
        const uint4* sp = (const uint4*)(Sb + ((size_t)row << 10));
        uint4 ua = sp[lane * 2], ub = sp[lane * 2 + 1];
        unsigned uu[8] = {ua.x, ua.y, ua.z, ua.w, ub.x, ub.y, ub.z, ub.w};
        float v[16];
        #pragma unroll
        for (int j = 0; j < 8; j++) {
            float2 f = __half22float2(*(__half2*)&uu[j]);
            v[2 * j] = f.x; v[2 * j + 1] = f.y;
        }
        float mx = -INFINITY;
        #pragma unroll
        for (int j = 0; j < 16; j++) { v[j] += dv[j]; mx = fmaxf(mx, v[j]); }
        mx = wave_max64(mx);
        float sum = 0.f;
        #pragma unroll
        for (int j = 0; j < 16; j++) sum += __expf(v[j] - mx);
        sum = wave_sum64(sum);
        if (lane == 0) {
            int i = row & 1023;
            float la = (mask[i] > 0.f) ? -__logf(nv[0]) : NEGV;
            outv[row] = la - (mx + __logf(sum));
        }
    }
}

// ---------------- transport: 8 rows/block, 2 rows/wave, shuffle-only ----------------
__global__ __launch_bounds__(256)
void transport_kernel(const __half* __restrict__ Sb, const float* __restrict__ f,
                      const float* __restrict__ g, const float* __restrict__ x_res,
                      float* __restrict__ xc) {
    int tid = threadIdx.x, lane = tid & 63, wid = tid >> 6;
    int row0 = blockIdx.x * 8;
    int h = row0 >> 10;
    const float4* gp = (const float4*)(g + ((size_t)h << 10));
    float gv[16];
    *(float4*)&gv[0]  = gp[lane * 4];     *(float4*)&gv[4]  = gp[lane * 4 + 1];
    *(float4*)&gv[8]  = gp[lane * 4 + 2]; *(float4*)&gv[12] = gp[lane * 4 + 3];
    float4 xv[12];                        // x_res floats [lane*48, lane*48+48)
    const float4* xp = (const float4*)x_res + lane * 12;
    #pragma unroll
    for (int k = 0; k < 12; k++) xv[k] = xp[k];
    const float* xf = (const float*)xv;
    #pragma unroll
    for (int r = 0; r < 2; r++) {
        int row = row0 + wid * 2 + r;
        float fr = f[row];
        const uint4* sp = (const uint4*)(Sb + ((size_t)row << 10));
        uint4 ua = sp[lane * 2], ub = sp[lane * 2 + 1];
        unsigned uu[8] = {ua.x, ua.y, ua.z, ua.w, ub.x, ub.y, ub.z, ub.w};
        float v[16];
        #pragma unroll
        for (int j = 0; j < 8; j++) {
            float2 fx = __half22float2(*(__half2*)&uu[j]);
            v[2 * j] = fx.x; v[2 * j + 1] = fx.y;
        }
        float mx = -INFINITY;
        #pragma unroll
        for (int j = 0; j < 16; j++) { v[j] += fr + gv[j]; mx = fmaxf(mx, v[j]); }
        mx = wave_max64(mx);
        float sum = 0.f, a0 = 0.f, a1 = 0.f, a2 = 0.f;
        #pragma unroll
        for (int j = 0; j < 16; j++) {
            float e = __expf(v[j] - mx);
            sum += e;
            a0 += e * xf[3 * j];
            a1 += e * xf[3 * j + 1];
            a2 += e * xf[3 * j + 2];
        }
        sum = wave_sum64(sum);
        a0 = wave_sum64(a0); a1 = wave_sum64(a1); a2 = wave_sum64(a2);
        if (lane == 0) {
            float inv = 1.f / sum;
            xc[(size_t)row * 3 + 0] = a0 * inv;
            xc[(size_t)row * 3 + 1] = a1 * inv;
            xc[(size_t)row * 3 + 2] = a2 * inv;
        }
    }
}

// ---------------- final: gate = sigmoid(LN(h2)@wg + b); x_out = x_res + gate*disp*mask ----
__global__ void final_kernel(const float* __restrict__ h2, const float* __restrict__ x_res,
                             const float* __restrict__ mask, const float* __restrict__ gm,
                             const float* __restrict__ bt, const float* __restrict__ wg,
                             const float* __restrict__ wb, const float* __restrict__ lamraw,
                             const float* __restrict__ xc, float* __restrict__ xout) {
    int n = blockIdx.x;
    int tid = threadIdx.x;
    __shared__ float red[256];
    const float* row = h2 + (size_t)n * DMODEL;
    float a = row[tid], b = row[tid + 256];
    red[tid] = a + b;
    __syncthreads();
    for (int off = 128; off; off >>= 1) { if (tid < off) red[tid] += red[tid + off]; __syncthreads(); }
    float mu = red[0] * (1.0f / DMODEL);
    __syncthreads();
    float d0 = a - mu, d1 = b - mu;
    red[tid] = d0 * d0 + d1 * d1;
    __syncthreads();
    for (int off = 128; off; off >>= 1) { if (tid < off) red[tid] += red[tid + off]; __syncthreads(); }
    float rstd = rsqrtf(red[0] * (1.0f / DMODEL) + 1e-5f);
    __syncthreads();
    float t0 = (d0 * rstd * gm[tid] + bt[tid]) * wg[tid];
    float t1 = (d1 * rstd * gm[tid + 256] + bt[tid + 256]) * wg[tid + 256];
    red[tid] = t0 + t1;
    __syncthreads();
    for (int off = 128; off; off >>= 1) { if (tid < off) red[tid] += red[tid + off]; __syncthreads(); }
    if (tid == 0) {
        float gate = 1.f / (1.f + expf(-(red[0] + wb[0])));
        float mk = mask[n];
        #pragma unroll
        for (int c = 0; c < 3; c++) {
            float xr = x_res[n * 3 + c];
            float disp = 0.f;
            for (int h = 0; h < NHEAD; h++) {
                float lam = tanhf(lamraw[h]) * (1.f / NHEAD);
                disp += lam * (xc[((size_t)h * NTOK + n) * 3 + c] - xr);
            }
            xout[n * 3 + c] = xr + gate * disp * mk;
        }
    }
}

extern "C" void kernel_launch(void* const* d_in, const int* in_sizes, int n_in,
                              void* d_out, int out_size, void* d_ws, size_t ws_size,
                              hipStream_t stream) {
    const float* h          = (const float*)d_in[0];
    const float* x_res      = (const float*)d_in[1];
    const int*   pos_bins   = (const int*)d_in[2];
    const float* mask       = (const float*)d_in[3];
    const float* ln_mha_g   = (const float*)d_in[4];
    const float* ln_mha_b   = (const float*)d_in[5];
    const float* w_q        = (const float*)d_in[6];
    const float* w_k        = (const float*)d_in[7];
    const float* w_v        = (const float*)d_in[8];
    const float* w_g        = (const float*)d_in[9];
    const float* w_o        = (const float*)d_in[10];
    const float* pos_w      = (const float*)d_in[11];
    const float* ln_ff_g    = (const float*)d_in[12];
    const float* ln_ff_b    = (const float*)d_in[13];
    const float* sw_w1      = (const float*)d_in[14];
    const float* sw_w3      = (const float*)d_in[15];
    const float* sw_w2      = (const float*)d_in[16];
    const float* ln_sink_g  = (const float*)d_in[17];
    const float* ln_sink_b  = (const float*)d_in[18];
    const float* w_q_sink   = (const float*)d_in[19];
    const float* w_k_sink   = (const float*)d_in[20];
    const float* alpha_h    = (const float*)d_in[21];
    const float* r_h        = (const float*)d_in[22];
    const float* eps        = (const float*)d_in[23];
    const float* ln_gate_g  = (const float*)d_in[24];
    const float* ln_gate_b  = (const float*)d_in[25];
    const float* w_gate_w   = (const float*)d_in[26];
    const float* w_gate_b   = (const float*)d_in[27];
    const float* lambda_raw = (const float*)d_in[28];
    float* out = (float*)d_out;
    const size_t ND = (size_t)NTOK * DMODEL;

    // ---- workspace bump allocator (256B aligned) ----
    char* Wp = (char*)d_ws;
    auto alloc = [&](size_t bytes) { char* p = Wp; Wp += (bytes + 255) & ~(size_t)255; return p; };
    unsigned short* wt_qkvg = (unsigned short*)alloc((size_t)2048 * 512 * 2);
    unsigned short* wt_o    = (unsigned short*)alloc((size_t)512 * 512 * 2);
    unsigned short* wt_13   = (unsigned short*)alloc((size_t)4096 * 512 * 2);
    unsigned short* wt_2    = (unsigned short*)alloc((size_t)512 * 2048 * 2);
    unsigned short* wt_qsks = (unsigned short*)alloc((size_t)1024 * 512 * 2);
    unsigned short* hnb     = (unsigned short*)alloc(ND * 2);
    float*          qkvg    = (float*)alloc((size_t)1024 * 2048 * 4);     // also reused as qs|ks f32
    unsigned short* attb    = (unsigned short*)alloc(ND * 2);
    float*          t1      = (float*)alloc(ND * 4);
    float*          h1      = (float*)alloc(ND * 4);
    unsigned short* ffb     = (unsigned short*)alloc((size_t)1024 * 2048 * 2);
    unsigned short* Qp      = (unsigned short*)alloc((size_t)16 * 1024 * 64 * 2);
    unsigned short* Kp      = (unsigned short*)alloc((size_t)16 * 1024 * 64 * 2);
    unsigned short* Vt      = (unsigned short*)alloc((size_t)16 * 32 * 1024 * 2);
    char*           R       = alloc((size_t)64 * 1024 * 1024);            // big shared region
    float*          fv      = (float*)alloc((size_t)16 * 1024 * 4);
    float*          gv      = (float*)alloc((size_t)16 * 1024 * 4);
    float*          xc      = (float*)alloc((size_t)16 * 1024 * 3 * 4);
    float*          nv      = (float*)alloc(256);

    __half* Sh_att = (__half*)R;                                // attention fp16 S -> bf16 P (32MB)
    float*  ff13   = (float*)R;                                 // FFN fused out (16MB)
    __half* Sh     = (__half*)R;                                // sinkhorn S fp16 (32MB)
    __half* Sth    = (__half*)(R + (size_t)32 * 1024 * 1024);   // sinkhorn S^T fp16 (32MB)
    float*  qsks   = qkvg;

    nvalid_kernel<<<1, 256, 0, stream>>>(mask, nv);

    // ---- weight prep (order-independent) ----
    wtrans_kernel<<<dim3(512/32, 512/32), 256, 0, stream>>>(w_q, wt_qkvg,                512, 512);
    wtrans_kernel<<<dim3(512/32, 512/32), 256, 0, stream>>>(w_k, wt_qkvg + 512*512,      512, 512);
    wtrans_kernel<<<dim3(512/32, 512/32), 256, 0, stream>>>(w_v, wt_qkvg + 2*512*512,    512, 512);
    wtrans_kernel<<<dim3(512/32, 512/32), 256, 0, stream>>>(w_g, wt_qkvg + 3*512*512,    512, 512);
    wtrans_kernel<<<dim3(512/32, 512/32), 256, 0, stream>>>(w_o, wt_o,                   512, 512);
    wtrans_kernel<<<dim3(2048/32, 512/32), 256, 0, stream>>>(sw_w1, wt_13,               512, 2048);
    wtrans_kernel<<<dim3(2048/32, 512/32), 256, 0, stream>>>(sw_w3, wt_13 + 2048*512,    512, 2048);
    wtrans_kernel<<<dim3(512/32, 2048/32), 256, 0, stream>>>(sw_w2, wt_2,                2048, 512);
    wtrans_kernel<<<dim3(512/32, 512/32), 256, 0, stream>>>(w_q_sink, wt_qsks,           512, 512);
    wtrans_kernel<<<dim3(512/32, 512/32), 256, 0, stream>>>(w_k_sink, wt_qsks + 512*512, 512, 512);

    // ---- MHA ----
    ln_bf16_kernel<<<NTOK, 256, 0, stream>>>(h, ln_mha_g, ln_mha_b, hnb);
    mfma_gemm<0><<<dim3(16, 8, 1), 256, 0, stream>>>(hnb, wt_qkvg, qkvg, nullptr, nullptr,
        2048, 512, 512, 512, 2048, 0, 0, 0, nullptr, nullptr, nullptr);
    qkpad_kernel<<<4096, 256, 0, stream>>>(qkvg, 2048, 0, 512, nullptr, nullptr, Qp, Kp);
    vtrans_kernel<<<dim3(32, 16), 256, 0, stream>>>(qkvg, Vt);
    mfma_gemm<3><<<dim3(8, 8, 16), 256, 0, stream>>>(Qp, Kp, nullptr, Sh_att, nullptr,
        1024, 64, 64, 64, 1024, 65536, 65536, 1048576, nullptr, nullptr, nullptr);
    bias_softmax_kernel<<<NTOK, 256, 0, stream>>>(Sh_att, pos_bins, pos_w, mask);
    // PV: A = bf16 P rows (in fp16 S buffer), Bt = Vt[h] (32 rows)
    mfma_gemm<2><<<dim3(1, 8, 16), 256, 0, stream>>>((const unsigned short*)Sh_att, Vt,
        nullptr, nullptr, attb,
        32, 1024, 1024, 1024, 512, 1048576, 32768, 32, nullptr, nullptr, nullptr);
    mfma_gemm<0><<<dim3(4, 8, 1), 256, 0, stream>>>(attb, wt_o, t1, nullptr, nullptr,
        512, 512, 512, 512, 512, 0, 0, 0, nullptr, nullptr, nullptr);
    mha_res_kernel<<<ND / 256, 256, 0, stream>>>(h, qkvg, t1, mask, h1);

    // ---- FFN ----
    ln_bf16_kernel<<<NTOK, 256, 0, stream>>>(h1, ln_ff_g, ln_ff_b, hnb);
    mfma_gemm<0><<<dim3(32, 8, 1), 256, 0, stream>>>(hnb, wt_13, ff13, nullptr, nullptr,
        4096, 512, 512, 512, 4096, 0, 0, 0, nullptr, nullptr, nullptr);
    silu_mul_kernel<<<(1024 * 2048) / 256, 256, 0, stream>>>(ff13, ffb);
    mfma_gemm<0><<<dim3(4, 8, 1), 256, 0, stream>>>(ffb, wt_2, t1, nullptr, nullptr,
        512, 2048, 2048, 2048, 512, 0, 0, 0, nullptr, nullptr, nullptr);
    ffn_res_kernel<<<ND / 256, 256, 0, stream>>>(h1, t1, mask, out);   // h2 -> out[0:ND]

    // ---- Sinkhorn ----
    ln_bf16_kernel<<<NTOK, 256, 0, stream>>>(out, ln_sink_g, ln_sink_b, hnb);
    mfma_gemm<0><<<dim3(8, 8, 1), 256, 0, stream>>>(hnb, wt_qsks, qsks, nullptr, nullptr,
        1024, 512, 512, 512, 1024, 0, 0, 0, nullptr, nullptr, nullptr);
    normvec_kernel<<<(NTOK * NHEAD) / 256, 256, 0, stream>>>(qsks);
    qkpad_kernel<<<4096, 256, 0, stream>>>(qsks, 1024, 0, 512, r_h, eps, Qp, Kp);
    mfma_gemm<1><<<dim3(8, 8, 16), 256, 0, stream>>>(Qp, Kp, nullptr, Sh, nullptr,
        1024, 64, 64, 64, 1024, 65536, 65536, 1048576, alpha_h, eps, mask);
    mfma_gemm<1><<<dim3(8, 8, 16), 256, 0, stream>>>(Kp, Qp, nullptr, Sth, nullptr,
        1024, 64, 64, 64, 1024, 65536, 65536, 1048576, alpha_h, eps, mask);

    hipMemsetAsync(gv, 0, NHEAD * NTOK * sizeof(float), stream);
    for (int it = 0; it < KIT; it++) {
        sink_pass_kernel<<<2048, 256, 0, stream>>>(Sh,  gv, mask, nv, fv);
        sink_pass_kernel<<<2048, 256, 0, stream>>>(Sth, fv, mask, nv, gv);
    }
    transport_kernel<<<2048, 256, 0, stream>>>(Sh, fv, gv, x_res, xc);

    final_kernel<<<NTOK, 256, 0, stream>>>(out, x_res, mask, ln_gate_g, ln_gate_b,
                                           w_gate_w, w_gate_b, lambda_raw, xc, out + ND);
}

// Round 5
// 700.675 us; speedup vs baseline: 5.3900x; 1.0759x over previous
//
#include <hip/hip_runtime.h>
#include <hip/hip_bf16.h>
#include <hip/hip_fp16.h>
#include <math.h>

#define NTOK 1024
#define DMODEL 512
#define NHEAD 16
#define DHEAD 32
#define DFF 2048
#define NBINS 68
#define KIT 20
#define NEGV (-1e9f)
#define NEGH (-30000.0f)   // masked logit sentinel for fp16 S storage

typedef __attribute__((ext_vector_type(8))) short bf16x8;
typedef __attribute__((ext_vector_type(4))) float f32x4;
typedef __attribute__((ext_vector_type(8))) unsigned short u16x8;

__device__ inline unsigned short f2bf(float f) {
    unsigned int u = __float_as_uint(f);
    unsigned int r = (u + 0x7fff + ((u >> 16) & 1)) >> 16;
    return (unsigned short)r;
}

__device__ inline float wave_max64(float v) {
    #pragma unroll
    for (int s = 32; s; s >>= 1) v = fmaxf(v, __shfl_xor(v, s, 64));
    return v;
}
__device__ inline float wave_sum64(float v) {
    #pragma unroll
    for (int s = 32; s; s >>= 1) v += __shfl_xor(v, s, 64);
    return v;
}

// ---------------- prep: all 10 weight transposes + nvalid/la/g-zero in ONE kernel --------
__global__ void prep_kernel(const float* __restrict__ w_q, const float* __restrict__ w_k,
                            const float* __restrict__ w_v, const float* __restrict__ w_g,
                            const float* __restrict__ w_o, const float* __restrict__ w_qs,
                            const float* __restrict__ w_ks, const float* __restrict__ sw1,
                            const float* __restrict__ sw3, const float* __restrict__ sw2,
                            unsigned short* __restrict__ wt_qkvg, unsigned short* __restrict__ wt_o,
                            unsigned short* __restrict__ wt_qsks, unsigned short* __restrict__ wt_13,
                            unsigned short* __restrict__ wt_2,
                            const float* __restrict__ mask, float* __restrict__ nv,
                            float* __restrict__ la, float* __restrict__ gv) {
    __shared__ float red[256];
    __shared__ float T[32][33];
    int b = blockIdx.x, tid = threadIdx.x;
    if (b >= 4864) {   // stats block: n_valid, log_a vector, zero g
        red[tid] = mask[tid] + mask[tid + 256] + mask[tid + 512] + mask[tid + 768];
        __syncthreads();
        for (int off = 128; off; off >>= 1) { if (tid < off) red[tid] += red[tid + off]; __syncthreads(); }
        float lognv = __logf(red[0]);
        if (tid == 0) nv[0] = red[0];
        for (int i = tid; i < NTOK; i += 256) la[i] = (mask[i] > 0.f) ? -lognv : NEGV;
        for (int i = tid; i < NHEAD * NTOK; i += 256) gv[i] = 0.f;
        return;
    }
    const float* W; unsigned short* D; int K, N, t;
    if (b < 1792) {
        int which = b >> 8; t = b & 255; K = 512; N = 512;
        switch (which) {
            case 0: W = w_q;  D = wt_qkvg; break;
            case 1: W = w_k;  D = wt_qkvg + 512 * 512; break;
            case 2: W = w_v;  D = wt_qkvg + 2 * 512 * 512; break;
            case 3: W = w_g;  D = wt_qkvg + 3 * 512 * 512; break;
            case 4: W = w_o;  D = wt_o; break;
            case 5: W = w_qs; D = wt_qsks; break;
            default: W = w_ks; D = wt_qsks + 512 * 512; break;
        }
    } else if (b < 2816) { W = sw1; D = wt_13;              K = 512;  N = 2048; t = b - 1792; }
    else if (b < 3840)   { W = sw3; D = wt_13 + 2048 * 512; K = 512;  N = 2048; t = b - 2816; }
    else                 { W = sw2; D = wt_2;               K = 2048; N = 512;  t = b - 3840; }
    int nx = N >> 5;
    int n0 = (t % nx) * 32, k0 = (t / nx) * 32;
    int r = tid >> 3, c0 = (tid & 7) * 4;
    float4 v4 = *(const float4*)&W[(size_t)(k0 + r) * N + n0 + c0];
    T[r][c0] = v4.x; T[r][c0 + 1] = v4.y; T[r][c0 + 2] = v4.z; T[r][c0 + 3] = v4.w;
    __syncthreads();
    ushort4 o;
    o.x = f2bf(T[c0][r]); o.y = f2bf(T[c0 + 1][r]);
    o.z = f2bf(T[c0 + 2][r]); o.w = f2bf(T[c0 + 3][r]);
    *(ushort4*)&D[(size_t)(n0 + r) * K + k0 + c0] = o;
}

// ---------------- LayerNorm -> bf16 out ----------------
__global__ void ln_bf16_kernel(const float* __restrict__ x, const float* __restrict__ gm,
                               const float* __restrict__ bt, unsigned short* __restrict__ out) {
    int n = blockIdx.x;
    int tid = threadIdx.x;
    __shared__ float red[256];
    const float* row = x + (size_t)n * DMODEL;
    float a = row[tid], b = row[tid + 256];
    red[tid] = a + b;
    __syncthreads();
    for (int off = 128; off; off >>= 1) { if (tid < off) red[tid] += red[tid + off]; __syncthreads(); }
    float mu = red[0] * (1.0f / DMODEL);
    __syncthreads();
    float d0 = a - mu, d1 = b - mu;
    red[tid] = d0 * d0 + d1 * d1;
    __syncthreads();
    for (int off = 128; off; off >>= 1) { if (tid < off) red[tid] += red[tid + off]; __syncthreads(); }
    float rstd = rsqrtf(red[0] * (1.0f / DMODEL) + 1e-5f);
    out[(size_t)n * DMODEL + tid]       = f2bf(d0 * rstd * gm[tid] + bt[tid]);
    out[(size_t)n * DMODEL + tid + 256] = f2bf(d1 * rstd * gm[tid + 256] + bt[tid + 256]);
}

// ---------------- fused residual + LayerNorm -> h_out f32, ln_out bf16 ----------------
// GATED=1: val = base + sigmoid-gate(fp16) * t1 * mask ; GATED=0: val = base + t1 * mask
template<int GATED>
__global__ void res_ln_kernel(const float* __restrict__ base, const __half* __restrict__ Gh,
                              const float* __restrict__ t1, const float* __restrict__ mask,
                              const float* __restrict__ gm, const float* __restrict__ bt,
                              float* __restrict__ hout, unsigned short* __restrict__ lnout) {
    int n = blockIdx.x, tid = threadIdx.x;
    __shared__ float red[256];
    float mk = mask[n];
    size_t off = (size_t)n * DMODEL;
    float a, b;
    if (GATED) {
        float g0 = __half2float(Gh[off + tid]);
        float g1 = __half2float(Gh[off + tid + 256]);
        a = base[off + tid]       + g0 * t1[off + tid]       * mk;
        b = base[off + tid + 256] + g1 * t1[off + tid + 256] * mk;
    } else {
        a = base[off + tid]       + t1[off + tid]       * mk;
        b = base[off + tid + 256] + t1[off + tid + 256] * mk;
    }
    hout[off + tid] = a; hout[off + tid + 256] = b;
    red[tid] = a + b;
    __syncthreads();
    for (int o2 = 128; o2; o2 >>= 1) { if (tid < o2) red[tid] += red[tid + o2]; __syncthreads(); }
    float mu = red[0] * (1.0f / DMODEL);
    __syncthreads();
    float d0 = a - mu, d1 = b - mu;
    red[tid] = d0 * d0 + d1 * d1;
    __syncthreads();
    for (int o2 = 128; o2; o2 >>= 1) { if (tid < o2) red[tid] += red[tid + o2]; __syncthreads(); }
    float rstd = rsqrtf(red[0] * (1.0f / DMODEL) + 1e-5f);
    lnout[off + tid]       = f2bf(d0 * rstd * gm[tid] + bt[tid]);
    lnout[off + tid + 256] = f2bf(d1 * rstd * gm[tid + 256] + bt[tid + 256]);
}

// ---------------- MFMA GEMM: C[M][*] = A[M][K] @ Bt[*][K]^T (bf16 in, f32 acc) ----------
// MODE 0: store f32 C.  MODE 1: v += alpha[h]/eps[h]; mask row/col -> NEGH; store fp16 Ch.
// MODE 2: store bf16 Cb, only cols < N (B rows clamped for staging).
// MODE 3: store fp16 Ch plain.
// MODE 4: QKVG epilogue -> Cb=Qp (scaled, padded), P2=Kp (padded), P3=Vt (transposed), Ch=sigmoid(G).
template<int MODE>
__global__ __launch_bounds__(256)
void mfma_gemm(const unsigned short* __restrict__ A, const unsigned short* __restrict__ Bt,
               float* __restrict__ C, __half* __restrict__ Ch, unsigned short* __restrict__ Cb,
               unsigned short* __restrict__ P2, unsigned short* __restrict__ P3,
               int N, int K, int lda, int ldb, int ldc,
               long sA, long sB, long sC,
               const float* __restrict__ alpha, const float* __restrict__ epsv,
               const float* __restrict__ mask) {
    __shared__ unsigned short As[128 * 64];
    __shared__ unsigned short Bs[128 * 64];
    const int h = blockIdx.z;
    A += (size_t)h * sA; Bt += (size_t)h * sB;
    const int tid = threadIdx.x;
    const int lane = tid & 63, wid = tid >> 6;
    const int wr = wid >> 1, wc = wid & 1;
    const int lr = lane & 15, kg = lane >> 4;
    const int row0 = blockIdx.y * 128, col0 = blockIdx.x * 128;
    f32x4 acc[4][4];
    #pragma unroll
    for (int i = 0; i < 4; i++)
        #pragma unroll
        for (int j = 0; j < 4; j++) acc[i][j] = (f32x4){0.f, 0.f, 0.f, 0.f};

    for (int k0 = 0; k0 < K; k0 += 64) {
        #pragma unroll
        for (int i = 0; i < 4; i++) {
            int cid = tid + i * 256;
            int r = cid >> 3, sl = cid & 7;
            int rb = col0 + r; if (rb > N - 1) rb = N - 1;   // clamp (PV: only 32 B-rows)
            u16x8 va = *(const u16x8*)&A[(size_t)(row0 + r) * lda + k0 + sl * 8];
            u16x8 vb = *(const u16x8*)&Bt[(size_t)rb * ldb + k0 + sl * 8];
            *(u16x8*)&As[r * 64 + ((sl ^ (r & 7)) * 8)] = va;
            *(u16x8*)&Bs[r * 64 + ((sl ^ (r & 7)) * 8)] = vb;
        }
        __syncthreads();
        #pragma unroll
        for (int ks = 0; ks < 2; ks++) {
            bf16x8 af[4], bfr[4];
            #pragma unroll
            for (int f = 0; f < 4; f++) {
                int ra = wr * 64 + f * 16 + lr;
                af[f] = *(const bf16x8*)&As[ra * 64 + (((ks * 4 + kg) ^ (ra & 7)) * 8)];
                int rb = wc * 64 + f * 16 + lr;
                bfr[f] = *(const bf16x8*)&Bs[rb * 64 + (((ks * 4 + kg) ^ (rb & 7)) * 8)];
            }
            #pragma unroll
            for (int i = 0; i < 4; i++)
                #pragma unroll
                for (int j = 0; j < 4; j++)
                    acc[i][j] = __builtin_amdgcn_mfma_f32_16x16x32_bf16(af[i], bfr[j], acc[i][j], 0, 0, 0);
        }
        __syncthreads();
    }
    float beta = 0.f;
    if (MODE == 1) beta = alpha[h] / epsv[h];
    #pragma unroll
    for (int i = 0; i < 4; i++) {
        int row = row0 + wr * 64 + i * 16 + kg * 4;
        #pragma unroll
        for (int j = 0; j < 4; j++) {
            int col = col0 + wc * 64 + j * 16 + lr;
            #pragma unroll
            for (int e = 0; e < 4; e++) {
                float v = acc[i][j][e];
                if (MODE == 0) {
                    C[(size_t)h * sC + (size_t)(row + e) * ldc + col] = v;
                } else if (MODE == 1) {
                    v += beta;
                    if (!(mask[row + e] > 0.f) || !(mask[col] > 0.f)) v = NEGH;
                    Ch[(size_t)h * sC + (size_t)(row + e) * ldc + col] = __float2half(v);
                } else if (MODE == 2) {
                    if (col < N)
                        Cb[(size_t)h * sC + (size_t)(row + e) * ldc + col] = f2bf(v);
                } else if (MODE == 3) {
                    Ch[(size_t)h * sC + (size_t)(row + e) * ldc + col] = __float2half(v);
                } else {
                    int region = col >> 9;          // block-uniform: 0=Q 1=K 2=V 3=G
                    int cc = col & 511;
                    int hh = cc >> 5, kk = cc & 31;
                    if (region == 0) {
                        size_t bidx = (((size_t)hh << 10) + (row + e)) * 64 + kk;
                        Cb[bidx] = f2bf(v * 0.17677669529663687f);
                        Cb[bidx + 32] = 0;
                    } else if (region == 1) {
                        size_t bidx = (((size_t)hh << 10) + (row + e)) * 64 + kk;
                        P2[bidx] = f2bf(v);
                        P2[bidx + 32] = 0;
                    } else if (region == 2) {
                        P3[(((size_t)hh * 32 + kk) << 10) + (row + e)] = f2bf(v);
                    } else {
                        Ch[(size_t)(row + e) * 512 + cc] = __float2half(1.f / (1.f + __expf(-v)));
                    }
                }
            }
        }
    }
}

// ---------------- FFN w1/w3 dual GEMM + silu*mul epilogue -> bf16 ffb ----------------
__global__ __launch_bounds__(256)
void ffn13_gemm(const unsigned short* __restrict__ A, const unsigned short* __restrict__ B1,
                const unsigned short* __restrict__ B2, unsigned short* __restrict__ outb) {
    __shared__ unsigned short As[128 * 64];
    __shared__ unsigned short B1s[128 * 64];
    __shared__ unsigned short B2s[128 * 64];
    const int tid = threadIdx.x;
    const int lane = tid & 63, wid = tid >> 6;
    const int wr = wid >> 1, wc = wid & 1;
    const int lr = lane & 15, kg = lane >> 4;
    const int row0 = blockIdx.y * 128, col0 = blockIdx.x * 128;
    f32x4 acc1[4][4], acc2[4][4];
    #pragma unroll
    for (int i = 0; i < 4; i++)
        #pragma unroll
        for (int j = 0; j < 4; j++) { acc1[i][j] = (f32x4){0,0,0,0}; acc2[i][j] = (f32x4){0,0,0,0}; }
    for (int k0 = 0; k0 < 512; k0 += 64) {
        #pragma unroll
        for (int i = 0; i < 4; i++) {
            int cid = tid + i * 256;
            int r = cid >> 3, sl = cid & 7;
            u16x8 va = *(const u16x8*)&A[(size_t)(row0 + r) * 512 + k0 + sl * 8];
            u16x8 v1 = *(const u16x8*)&B1[(size_t)(col0 + r) * 512 + k0 + sl * 8];
            u16x8 v2 = *(const u16x8*)&B2[(size_t)(col0 + r) * 512 + k0 + sl * 8];
            *(u16x8*)&As[r * 64 + ((sl ^ (r & 7)) * 8)] = va;
            *(u16x8*)&B1s[r * 64 + ((sl ^ (r & 7)) * 8)] = v1;
            *(u16x8*)&B2s[r * 64 + ((sl ^ (r & 7)) * 8)] = v2;
        }
        __syncthreads();
        #pragma unroll
        for (int ks = 0; ks < 2; ks++) {
            bf16x8 af[4], b1f[4], b2f[4];
            #pragma unroll
            for (int f = 0; f < 4; f++) {
                int ra = wr * 64 + f * 16 + lr;
                af[f] = *(const bf16x8*)&As[ra * 64 + (((ks * 4 + kg) ^ (ra & 7)) * 8)];
                int rb = wc * 64 + f * 16 + lr;
                b1f[f] = *(const bf16x8*)&B1s[rb * 64 + (((ks * 4 + kg) ^ (rb & 7)) * 8)];
                b2f[f] = *(const bf16x8*)&B2s[rb * 64 + (((ks * 4 + kg) ^ (rb & 7)) * 8)];
            }
            #pragma unroll
            for (int i = 0; i < 4; i++)
                #pragma unroll
                for (int j = 0; j < 4; j++) {
                    acc1[i][j] = __builtin_amdgcn_mfma_f32_16x16x32_bf16(af[i], b1f[j], acc1[i][j], 0, 0, 0);
                    acc2[i][j] = __builtin_amdgcn_mfma_f32_16x16x32_bf16(af[i], b2f[j], acc2[i][j], 0, 0, 0);
                }
        }
        __syncthreads();
    }
    #pragma unroll
    for (int i = 0; i < 4; i++) {
        int row = row0 + wr * 64 + i * 16 + kg * 4;
        #pragma unroll
        for (int j = 0; j < 4; j++) {
            int col = col0 + wc * 64 + j * 16 + lr;
            #pragma unroll
            for (int e = 0; e < 4; e++) {
                float x = acc1[i][j][e], y = acc2[i][j][e];
                outb[(size_t)(row + e) * 2048 + col] = f2bf(x / (1.f + __expf(-x)) * y);
            }
        }
    }
}

// ---------------- attention: bias + mask + softmax over fp16 S; writes bf16 P in place ----
__global__ __launch_bounds__(256)
void bias_softmax_kernel(__half* __restrict__ S, const int* __restrict__ pos_bins,
                         const float* __restrict__ pos_w, const float* __restrict__ mask) {
    __shared__ int   bins_s[NTOK];
    __shared__ float pw_s[NBINS * NHEAD];
    int n = blockIdx.x, tid = threadIdx.x;
    int lane = tid & 63, wid = tid >> 6;
    #pragma unroll
    for (int i = 0; i < 4; i++) {
        int m = tid + i * 256;
        int b = pos_bins[(size_t)n * NTOK + m];
        bins_s[m] = (mask[m] > 0.f) ? b : -1;
    }
    #pragma unroll
    for (int i = 0; i < 5; i++) {
        int idx = tid + i * 256;
        if (idx < NBINS * NHEAD) pw_s[idx] = pos_w[idx];
    }
    __syncthreads();
    int mb = lane * 16;
    #pragma unroll
    for (int hh = 0; hh < 4; hh++) {
        int h = wid * 4 + hh;
        __half* row = S + ((size_t)h * NTOK + n) * NTOK;
        uint4 ua = ((const uint4*)row)[lane * 2];
        uint4 ub = ((const uint4*)row)[lane * 2 + 1];
        unsigned uu[8] = {ua.x, ua.y, ua.z, ua.w, ub.x, ub.y, ub.z, ub.w};
        float v[16];
        #pragma unroll
        for (int j = 0; j < 8; j++) {
            float2 f = __half22float2(*(__half2*)&uu[j]);
            v[2 * j] = f.x; v[2 * j + 1] = f.y;
        }
        float mx = -INFINITY;
        #pragma unroll
        for (int j = 0; j < 16; j++) {
            int b = bins_s[mb + j];
            v[j] = (b >= 0) ? v[j] + pw_s[b * NHEAD + h] : NEGV;
            mx = fmaxf(mx, v[j]);
        }
        mx = wave_max64(mx);
        float sum = 0.f;
        #pragma unroll
        for (int j = 0; j < 16; j++) { v[j] = __expf(v[j] - mx); sum += v[j]; }
        float inv = 1.f / wave_sum64(sum);
        unsigned short o[16];
        #pragma unroll
        for (int j = 0; j < 16; j++) o[j] = f2bf(v[j] * inv);
        ((uint4*)row)[lane * 2]     = *(uint4*)&o[0];
        ((uint4*)row)[lane * 2 + 1] = *(uint4*)&o[8];
    }
}

// ---------------- sinkhorn Qs/Ks: normalize + scale + pad to [H][N][64] bf16 -------------
__global__ void norm_pad_kernel(const float* __restrict__ qsks, const float* __restrict__ rh,
                                const float* __restrict__ ev,
                                unsigned short* __restrict__ Qp, unsigned short* __restrict__ Kp) {
    int idx = blockIdx.x * 256 + threadIdx.x;   // 16384 = h*1024 + n
    int h = idx >> 10, n = idx & 1023;
    const float* q = &qsks[(size_t)n * 1024 + h * 32];
    const float* k = q + 512;
    float s = rh[h] / ev[h];
    float qv[32], kv[32];
    float ssq = 0.f, ssk = 0.f;
    #pragma unroll
    for (int d = 0; d < 32; d++) {
        qv[d] = q[d]; ssq += qv[d] * qv[d];
        kv[d] = k[d]; ssk += kv[d] * kv[d];
    }
    float iq = s / fmaxf(sqrtf(ssq), 1e-12f);
    float ik = 1.f / fmaxf(sqrtf(ssk), 1e-12f);
    size_t base = (size_t)idx * 64;
    #pragma unroll
    for (int d = 0; d < 32; d++) {
        Qp[base + d] = f2bf(qv[d] * iq);
        Kp[base + d] = f2bf(kv[d] * ik);
        Qp[base + 32 + d] = 0;
        Kp[base + 32 + d] = 0;
    }
}

// ---------------- sinkhorn pass: 8 rows/block, 2 rows/wave, shuffle-only reductions ------
__global__ __launch_bounds__(256)
void sink_pass_kernel(const __half* __restrict__ Sb, const float* __restrict__ dual,
                      const float* __restrict__ la, float* __restrict__ outv) {
    int tid = threadIdx.x, lane = tid & 63, wid = tid >> 6;
    int row0 = blockIdx.x * 8;
    int h = row0 >> 10;
    const float4* dp = (const float4*)(dual + ((size_t)h << 10));
    float dv[16];
    *(float4*)&dv[0]  = dp[lane * 4];     *(float4*)&dv[4]  = dp[lane * 4 + 1];
    *(float4*)&dv[8]  = dp[lane * 4 + 2]; *(float4*)&dv[12] = dp[lane * 4 + 3];
    #pragma unroll
    for (int r = 0; r < 2; r++) {
        int row = row0 + wid * 2 + r;
        const uint4* sp = (const uint4*)(Sb + ((size_t)row << 10));
        uint4 ua = sp[lane * 2], ub = sp[lane * 2 + 1];
        unsigned uu[8] = {ua.x, ua.y, ua.z, ua.w, ub.x, ub.y, ub.z, ub.w};
        float v[16];
        #pragma unroll
        for (int j = 0; j < 8; j++) {
            float2 f = __half22float2(*(__half2*)&uu[j]);
            v[2 * j] = f.x; v[2 * j + 1] = f.y;
        }
        float mx = -INFINITY;
        #pragma unroll
        for (int j = 0; j < 16; j++) { v[j] += dv[j]; mx = fmaxf(mx, v[j]); }
        mx = wave_max64(mx);
        float sum = 0.f;
        #pragma unroll
        for (int j = 0; j < 16; j++) sum += __expf(v[j] - mx);
        sum = wave_sum64(sum);
        if (lane == 0) outv[row] = la[row & 1023] - (mx + __logf(sum));
    }
}

// ---------------- transport: 8 rows/block, 2 rows/wave, shuffle-only ----------------
__global__ __launch_bounds__(256)
void transport_kernel(const __half* __restrict__ Sb, const float* __restrict__ f,
                      const float* __restrict__ g, const float* __restrict__ x_res,
                      float* __restrict__ xc) {
    int tid = threadIdx.x, lane = tid & 63, wid = tid >> 6;
    int row0 = blockIdx.x * 8;
    int h = row0 >> 10;
    const float4* gp = (const float4*)(g + ((size_t)h << 10));
    float gv[16];
    *(float4*)&gv[0]  = gp[lane * 4];     *(float4*)&gv[4]  = gp[lane * 4 + 1];
    *(float4*)&gv[8]  = gp[lane * 4 + 2]; *(float4*)&gv[12] = gp[lane * 4 + 3];
    float4 xv[12];
    const float4* xp = (const float4*)x_res + lane * 12;
    #pragma unroll
    for (int k = 0; k < 12; k++) xv[k] = xp[k];
    const float* xf = (const float*)xv;
    #pragma unroll
    for (int r = 0; r < 2; r++) {
        int row = row0 + wid * 2 + r;
        float fr = f[row];
        const uint4* sp = (const uint4*)(Sb + ((size_t)row << 10));
        uint4 ua = sp[lane * 2], ub = sp[lane * 2 + 1];
        unsigned uu[8] = {ua.x, ua.y, ua.z, ua.w, ub.x, ub.y, ub.z, ub.w};
        float v[16];
        #pragma unroll
        for (int j = 0; j < 8; j++) {
            float2 fx = __half22float2(*(__half2*)&uu[j]);
            v[2 * j] = fx.x; v[2 * j + 1] = fx.y;
        }
        float mx = -INFINITY;
        #pragma unroll
        for (int j = 0; j < 16; j++) { v[j] += fr + gv[j]; mx = fmaxf(mx, v[j]); }
        mx = wave_max64(mx);
        float sum = 0.f, a0 = 0.f, a1 = 0.f, a2 = 0.f;
        #pragma unroll
        for (int j = 0; j < 16; j++) {
            float e = __expf(v[j] - mx);
            sum += e;
            a0 += e * xf[3 * j];
            a1 += e * xf[3 * j + 1];
            a2 += e * xf[3 * j + 2];
        }
        sum = wave_sum64(sum);
        a0 = wave_sum64(a0); a1 = wave_sum64(a1); a2 = wave_sum64(a2);
        if (lane == 0) {
            float inv = 1.f / sum;
            xc[(size_t)row * 3 + 0] = a0 * inv;
            xc[(size_t)row * 3 + 1] = a1 * inv;
            xc[(size_t)row * 3 + 2] = a2 * inv;
        }
    }
}

// ---------------- final: gate = sigmoid(LN(h2)@wg + b); x_out = x_res + gate*disp*mask ----
__global__ void final_kernel(const float* __restrict__ h2, const float* __restrict__ x_res,
                             const float* __restrict__ mask, const float* __restrict__ gm,
                             const float* __restrict__ bt, const float* __restrict__ wg,
                             const float* __restrict__ wb, const float* __restrict__ lamraw,
                             const float* __restrict__ xc, float* __restrict__ xout) {
    int n = blockIdx.x;
    int tid = threadIdx.x;
    __shared__ float red[256];
    const float* row = h2 + (size_t)n * DMODEL;
    float a = row[tid], b = row[tid + 256];
    red[tid] = a + b;
    __syncthreads();
    for (int off = 128; off; off >>= 1) { if (tid < off) red[tid] += red[tid + off]; __syncthreads(); }
    float mu = red[0] * (1.0f / DMODEL);
    __syncthreads();
    float d0 = a - mu, d1 = b - mu;
    red[tid] = d0 * d0 + d1 * d1;
    __syncthreads();
    for (int off = 128; off; off >>= 1) { if (tid < off) red[tid] += red[tid + off]; __syncthreads(); }
    float rstd = rsqrtf(red[0] * (1.0f / DMODEL) + 1e-5f);
    __syncthreads();
    float t0 = (d0 * rstd * gm[tid] + bt[tid]) * wg[tid];
    float t1 = (d1 * rstd * gm[tid + 256] + bt[tid + 256]) * wg[tid + 256];
    red[tid] = t0 + t1;
    __syncthreads();
    for (int off = 128; off; off >>= 1) { if (tid < off) red[tid] += red[tid + off]; __syncthreads(); }
    if (tid == 0) {
        float gate = 1.f / (1.f + expf(-(red[0] + wb[0])));
        float mk = mask[n];
        #pragma unroll
        for (int c = 0; c < 3; c++) {
            float xr = x_res[n * 3 + c];
            float disp = 0.f;
            for (int h = 0; h < NHEAD; h++) {
                float lam = tanhf(lamraw[h]) * (1.f / NHEAD);
                disp += lam * (xc[((size_t)h * NTOK + n) * 3 + c] - xr);
            }
            xout[n * 3 + c] = xr + gate * disp * mk;
        }
    }
}

extern "C" void kernel_launch(void* const* d_in, const int* in_sizes, int n_in,
                              void* d_out, int out_size, void* d_ws, size_t ws_size,
                              hipStream_t stream) {
    const float* h          = (const float*)d_in[0];
    const float* x_res      = (const float*)d_in[1];
    const int*   pos_bins   = (const int*)d_in[2];
    const float* mask       = (const float*)d_in[3];
    const float* ln_mha_g   = (const float*)d_in[4];
    const float* ln_mha_b   = (const float*)d_in[5];
    const float* w_q        = (const float*)d_in[6];
    const float* w_k        = (const float*)d_in[7];
    const float* w_v        = (const float*)d_in[8];
    const float* w_g        = (const float*)d_in[9];
    const float* w_o        = (const float*)d_in[10];
    const float* pos_w      = (const float*)d_in[11];
    const float* ln_ff_g    = (const float*)d_in[12];
    const float* ln_ff_b    = (const float*)d_in[13];
    const float* sw_w1      = (const float*)d_in[14];
    const float* sw_w3      = (const float*)d_in[15];
    const float* sw_w2      = (const float*)d_in[16];
    const float* ln_sink_g  = (const float*)d_in[17];
    const float* ln_sink_b  = (const float*)d_in[18];
    const float* w_q_sink   = (const float*)d_in[19];
    const float* w_k_sink   = (const float*)d_in[20];
    const float* alpha_h    = (const float*)d_in[21];
    const float* r_h        = (const float*)d_in[22];
    const float* eps        = (const float*)d_in[23];
    const float* ln_gate_g  = (const float*)d_in[24];
    const float* ln_gate_b  = (const float*)d_in[25];
    const float* w_gate_w   = (const float*)d_in[26];
    const float* w_gate_b   = (const float*)d_in[27];
    const float* lambda_raw = (const float*)d_in[28];
    float* out = (float*)d_out;
    const size_t ND = (size_t)NTOK * DMODEL;

    // ---- workspace bump allocator (256B aligned) ----
    char* Wp = (char*)d_ws;
    auto alloc = [&](size_t bytes) { char* p = Wp; Wp += (bytes + 255) & ~(size_t)255; return p; };
    unsigned short* wt_qkvg = (unsigned short*)alloc((size_t)2048 * 512 * 2);
    unsigned short* wt_o    = (unsigned short*)alloc((size_t)512 * 512 * 2);
    unsigned short* wt_13   = (unsigned short*)alloc((size_t)4096 * 512 * 2);
    unsigned short* wt_2    = (unsigned short*)alloc((size_t)512 * 2048 * 2);
    unsigned short* wt_qsks = (unsigned short*)alloc((size_t)1024 * 512 * 2);
    unsigned short* hnb     = (unsigned short*)alloc(ND * 2);
    __half*         Gh      = (__half*)alloc(ND * 2);
    unsigned short* attb    = (unsigned short*)alloc(ND * 2);
    float*          t1      = (float*)alloc(ND * 4);
    float*          h1      = (float*)alloc(ND * 4);
    unsigned short* ffb     = (unsigned short*)alloc((size_t)1024 * 2048 * 2);
    unsigned short* Qp      = (unsigned short*)alloc((size_t)16 * 1024 * 64 * 2);
    unsigned short* Kp      = (unsigned short*)alloc((size_t)16 * 1024 * 64 * 2);
    unsigned short* Vt      = (unsigned short*)alloc((size_t)16 * 32 * 1024 * 2);
    float*          qsks    = (float*)alloc((size_t)1024 * 1024 * 4);
    char*           R       = alloc((size_t)64 * 1024 * 1024);
    float*          fv      = (float*)alloc((size_t)16 * 1024 * 4);
    float*          gv      = (float*)alloc((size_t)16 * 1024 * 4);
    float*          la      = (float*)alloc((size_t)1024 * 4);
    float*          xc      = (float*)alloc((size_t)16 * 1024 * 3 * 4);
    float*          nv      = (float*)alloc(256);

    __half* Sh_att = (__half*)R;                                // attention fp16 S -> bf16 P (32MB)
    __half* Sh     = (__half*)R;                                // sinkhorn S fp16 (32MB)
    __half* Sth    = (__half*)(R + (size_t)32 * 1024 * 1024);   // sinkhorn S^T fp16 (32MB)

    // ---- prep: 10 weight transposes + n_valid + la + g=0 ----
    prep_kernel<<<4865, 256, 0, stream>>>(w_q, w_k, w_v, w_g, w_o, w_q_sink, w_k_sink,
                                          sw_w1, sw_w3, sw_w2,
                                          wt_qkvg, wt_o, wt_qsks, wt_13, wt_2,
                                          mask, nv, la, gv);

    // ---- MHA ----
    ln_bf16_kernel<<<NTOK, 256, 0, stream>>>(h, ln_mha_g, ln_mha_b, hnb);
    mfma_gemm<4><<<dim3(16, 8, 1), 256, 0, stream>>>(hnb, wt_qkvg, nullptr, Gh, Qp, Kp, Vt,
        2048, 512, 512, 512, 2048, 0, 0, 0, nullptr, nullptr, nullptr);
    mfma_gemm<3><<<dim3(8, 8, 16), 256, 0, stream>>>(Qp, Kp, nullptr, Sh_att, nullptr, nullptr, nullptr,
        1024, 64, 64, 64, 1024, 65536, 65536, 1048576, nullptr, nullptr, nullptr);
    bias_softmax_kernel<<<NTOK, 256, 0, stream>>>(Sh_att, pos_bins, pos_w, mask);
    mfma_gemm<2><<<dim3(1, 8, 16), 256, 0, stream>>>((const unsigned short*)Sh_att, Vt,
        nullptr, nullptr, attb, nullptr, nullptr,
        32, 1024, 1024, 1024, 512, 1048576, 32768, 32, nullptr, nullptr, nullptr);
    mfma_gemm<0><<<dim3(4, 8, 1), 256, 0, stream>>>(attb, wt_o, t1, nullptr, nullptr, nullptr, nullptr,
        512, 512, 512, 512, 512, 0, 0, 0, nullptr, nullptr, nullptr);
    res_ln_kernel<1><<<NTOK, 256, 0, stream>>>(h, Gh, t1, mask, ln_ff_g, ln_ff_b, h1, hnb);

    // ---- FFN ----
    ffn13_gemm<<<dim3(16, 8), 256, 0, stream>>>(hnb, wt_13, wt_13 + 2048 * 512, ffb);
    mfma_gemm<0><<<dim3(4, 8, 1), 256, 0, stream>>>(ffb, wt_2, t1, nullptr, nullptr, nullptr, nullptr,
        512, 2048, 2048, 2048, 512, 0, 0, 0, nullptr, nullptr, nullptr);
    res_ln_kernel<0><<<NTOK, 256, 0, stream>>>(h1, nullptr, t1, mask, ln_sink_g, ln_sink_b, out, hnb);

    // ---- Sinkhorn ----
    mfma_gemm<0><<<dim3(8, 8, 1), 256, 0, stream>>>(hnb, wt_qsks, qsks, nullptr, nullptr, nullptr, nullptr,
        1024, 512, 512, 512, 1024, 0, 0, 0, nullptr, nullptr, nullptr);
    norm_pad_kernel<<<64, 256, 0, stream>>>(qsks, r_h, eps, Qp, Kp);
    mfma_gemm<1><<<dim3(8, 8, 16), 256, 0, stream>>>(Qp, Kp, nullptr, Sh, nullptr, nullptr, nullptr,
        1024, 64, 64, 64, 1024, 65536, 65536, 1048576, alpha_h, eps, mask);
    mfma_gemm<1><<<dim3(8, 8, 16), 256, 0, stream>>>(Kp, Qp, nullptr, Sth, nullptr, nullptr, nullptr,
        1024, 64, 64, 64, 1024, 65536, 65536, 1048576, alpha_h, eps, mask);

    for (int it = 0; it < KIT; it++) {
        sink_pass_kernel<<<2048, 256, 0, stream>>>(Sh,  gv, la, fv);
        sink_pass_kernel<<<2048, 256, 0, stream>>>(Sth, fv, la, gv);
    }
    transport_kernel<<<2048, 256, 0, stream>>>(Sh, fv, gv, x_res, xc);

    final_kernel<<<NTOK, 256, 0, stream>>>(out, x_res, mask, ln_gate_g, ln_gate_b,
                                           w_gate_w, w_gate_b, lambda_raw, xc, out + ND);
}